// Round 1
// baseline (38866.415 us; speedup 1.0000x reference)
//
#include <hip/hip_runtime.h>
#include <math.h>

#define VSZ 50257
#define NLAYER 12
#define NH 12
#define EMB 768
#define TSEQ 1024
#define NB 4
#define MROWS (NB * TSEQ)   // 4096
#define DHEAD 64
#define LN_EPS 1e-5f

// ---------------- embedding: x[b,t,:] = wte[idx[b,t],:] + wpe[t,:] ----------------
__global__ void embed_kernel(const int* __restrict__ idx, const float* __restrict__ wte,
                             const float* __restrict__ wpe, float* __restrict__ x) {
    int row = blockIdx.x;                 // 0..MROWS-1
    int t = row & (TSEQ - 1);
    int tok = idx[row];
    const float* wt = wte + (size_t)tok * EMB;
    const float* wp = wpe + (size_t)t * EMB;
    float* xo = x + (size_t)row * EMB;
    for (int e = threadIdx.x; e < EMB; e += blockDim.x)
        xo[e] = wt[e] + wp[e];
}

// ---------------- layernorm over last dim (E=768), one block (256 thr) per row ----------------
__global__ void ln_kernel(const float* __restrict__ x, const float* __restrict__ g,
                          const float* __restrict__ b, float* __restrict__ out) {
    int row = blockIdx.x;
    const float* xr = x + (size_t)row * EMB;
    float* yr = out + (size_t)row * EMB;
    int tid = threadIdx.x;
    float v0 = xr[tid], v1 = xr[tid + 256], v2 = xr[tid + 512];
    float s = v0 + v1 + v2;
    float ss = v0 * v0 + v1 * v1 + v2 * v2;
    // wave (64-lane) reduce, then cross-wave via LDS
    #pragma unroll
    for (int i = 1; i < 64; i <<= 1) {
        s  += __shfl_xor(s, i, 64);
        ss += __shfl_xor(ss, i, 64);
    }
    __shared__ float sm[4], sv[4];
    int lane = tid & 63, wid = tid >> 6;
    if (lane == 0) { sm[wid] = s; sv[wid] = ss; }
    __syncthreads();
    float sum = sm[0] + sm[1] + sm[2] + sm[3];
    float sqs = sv[0] + sv[1] + sv[2] + sv[3];
    float mean = sum * (1.0f / EMB);
    float var = sqs * (1.0f / EMB) - mean * mean;
    float rstd = rsqrtf(var + LN_EPS);
    yr[tid]       = (v0 - mean) * rstd * g[tid]       + b[tid];
    yr[tid + 256] = (v1 - mean) * rstd * g[tid + 256] + b[tid + 256];
    yr[tid + 512] = (v2 - mean) * rstd * g[tid + 512] + b[tid + 512];
}

// ---------------- generic fp32 tiled GEMM: C[M,N] = act(A[M,K] @ B + bias) + res ----------------
// TRANSB=false: B is [K,N] row-major. TRANSB=true: B is [N,K] row-major (lm_head: wte).
template <bool TRANSB, bool GELU>
__global__ void gemm_kernel(const float* __restrict__ A, const float* __restrict__ B,
                            const float* __restrict__ bias, const float* __restrict__ res,
                            float* __restrict__ C, int M, int N, int K) {
    const int BM = 64, BN = 64, BK = 16;
    __shared__ float As[BK][BM + 1];
    __shared__ float Bs[BK][BN + 1];
    int tx = threadIdx.x & 15, ty = threadIdx.x >> 4;
    int m0 = blockIdx.y * BM, n0 = blockIdx.x * BN;
    float acc[4][4] = {};
    for (int k0 = 0; k0 < K; k0 += BK) {
        // A tile 64x16: consecutive tid -> consecutive k (contiguous in A)
        for (int t = threadIdx.x; t < BM * BK; t += 256) {
            int i = t >> 4, j = t & 15;
            int m = m0 + i, k = k0 + j;
            As[j][i] = (m < M && k < K) ? A[(size_t)m * K + k] : 0.0f;
        }
        if (!TRANSB) {
            // B tile 16x64: consecutive tid -> consecutive n (contiguous in B)
            for (int t = threadIdx.x; t < BK * BN; t += 256) {
                int i = t >> 6, j = t & 63;
                int k = k0 + i, n = n0 + j;
                Bs[i][j] = (k < K && n < N) ? B[(size_t)k * N + n] : 0.0f;
            }
        } else {
            // B is [N,K]: consecutive tid -> consecutive k (contiguous in B row)
            for (int t = threadIdx.x; t < BK * BN; t += 256) {
                int i = t & 15, j = t >> 4;
                int k = k0 + i, n = n0 + j;
                Bs[i][j] = (k < K && n < N) ? B[(size_t)n * K + k] : 0.0f;
            }
        }
        __syncthreads();
        #pragma unroll
        for (int kk = 0; kk < BK; ++kk) {
            float a[4], bv[4];
            #pragma unroll
            for (int i = 0; i < 4; i++) a[i] = As[kk][ty * 4 + i];
            #pragma unroll
            for (int j = 0; j < 4; j++) bv[j] = Bs[kk][tx * 4 + j];
            #pragma unroll
            for (int i = 0; i < 4; i++)
                #pragma unroll
                for (int j = 0; j < 4; j++) acc[i][j] += a[i] * bv[j];
        }
        __syncthreads();
    }
    #pragma unroll
    for (int i = 0; i < 4; i++) {
        int m = m0 + ty * 4 + i;
        if (m >= M) continue;
        #pragma unroll
        for (int j = 0; j < 4; j++) {
            int n = n0 + tx * 4 + j;
            if (n >= N) continue;
            float v = acc[i][j];
            if (bias) v += bias[n];
            if (GELU) {
                float c = 0.7978845608028654f * (v + 0.044715f * v * v * v);
                v = 0.5f * v * (1.0f + tanhf(c));
            }
            if (res) v += res[(size_t)m * N + n];
            C[(size_t)m * N + n] = v;
        }
    }
}

// ---------------- causal attention, one wave per (q, h, b) ----------------
// qkv: [B*T, 3E]. y out: [B*T, E] (already merged heads).
__global__ void attn_kernel(const float* __restrict__ qkv, float* __restrict__ y) {
    int q = blockIdx.x;   // 0..T-1
    int h = blockIdx.y;   // 0..H-1
    int b = blockIdx.z;   // 0..B-1
    int tid = threadIdx.x;  // 0..63
    __shared__ float qs[DHEAD];
    __shared__ float p[TSEQ];

    const size_t rowstride = 3 * EMB;
    const float* qrow = qkv + ((size_t)(b * TSEQ + q)) * rowstride + h * DHEAD;
    qs[tid] = qrow[tid];
    __syncthreads();

    // phase 1: scores for this thread's k's, track local max
    float mloc = -INFINITY;
    for (int k = tid; k <= q; k += 64) {
        const float* krow = qkv + ((size_t)(b * TSEQ + k)) * rowstride + EMB + h * DHEAD;
        float s = 0.0f;
        #pragma unroll
        for (int d = 0; d < DHEAD; d++) s += qs[d] * krow[d];
        s *= 0.125f;  // 1/sqrt(64)
        p[k] = s;
        mloc = fmaxf(mloc, s);
    }
    #pragma unroll
    for (int i = 1; i < 64; i <<= 1) mloc = fmaxf(mloc, __shfl_xor(mloc, i, 64));
    // phase 2: exp + sum
    float sloc = 0.0f;
    for (int k = tid; k <= q; k += 64) {
        float e = expf(p[k] - mloc);
        p[k] = e;
        sloc += e;
    }
    #pragma unroll
    for (int i = 1; i < 64; i <<= 1) sloc += __shfl_xor(sloc, i, 64);
    float inv = 1.0f / sloc;
    __syncthreads();
    // phase 3: out[d] = sum_k p[k] * V[k,d]; lane owns d
    const float* vbase = qkv + (size_t)b * TSEQ * rowstride + 2 * EMB + h * DHEAD + tid;
    float acc = 0.0f;
    for (int k = 0; k <= q; k++) acc += p[k] * vbase[(size_t)k * rowstride];
    y[((size_t)(b * TSEQ + q)) * EMB + h * DHEAD + tid] = acc * inv;
}

// ---------------- launcher ----------------
extern "C" void kernel_launch(void* const* d_in, const int* in_sizes, int n_in,
                              void* d_out, int out_size, void* d_ws, size_t ws_size,
                              hipStream_t stream) {
    const int*   idx     = (const int*)d_in[0];
    const float* wte     = (const float*)d_in[1];
    const float* wpe     = (const float*)d_in[2];
    const float* ln1_g   = (const float*)d_in[3];
    const float* ln1_b   = (const float*)d_in[4];
    const float* attn_w  = (const float*)d_in[5];
    const float* attn_b  = (const float*)d_in[6];
    const float* proj_w  = (const float*)d_in[7];
    const float* proj_b  = (const float*)d_in[8];
    const float* ln2_g   = (const float*)d_in[9];
    const float* ln2_b   = (const float*)d_in[10];
    const float* fc_w    = (const float*)d_in[11];
    const float* fc_b    = (const float*)d_in[12];
    const float* mproj_w = (const float*)d_in[13];
    const float* mproj_b = (const float*)d_in[14];
    const float* lnf_g   = (const float*)d_in[15];
    const float* lnf_b   = (const float*)d_in[16];
    float* out = (float*)d_out;

    // workspace layout (floats); g aliases qkv+y (dead by MLP time)
    float* x   = (float*)d_ws;                    // MROWS*EMB
    float* h   = x + (size_t)MROWS * EMB;         // MROWS*EMB
    float* qkv = h + (size_t)MROWS * EMB;         // MROWS*3*EMB
    float* y   = qkv + (size_t)MROWS * 3 * EMB;   // MROWS*EMB
    float* g   = qkv;                             // MROWS*4*EMB (aliases qkv+y)

    dim3 blk256(256);
    embed_kernel<<<MROWS, blk256, 0, stream>>>(idx, wte, wpe, x);

    for (int l = 0; l < NLAYER; l++) {
        const float* aw = attn_w + (size_t)l * EMB * 3 * EMB;
        const float* ab = attn_b + (size_t)l * 3 * EMB;
        const float* pw = proj_w + (size_t)l * EMB * EMB;
        const float* pb = proj_b + (size_t)l * EMB;
        const float* fw = fc_w   + (size_t)l * EMB * 4 * EMB;
        const float* fb = fc_b   + (size_t)l * 4 * EMB;
        const float* mw = mproj_w + (size_t)l * 4 * EMB * EMB;
        const float* mb = mproj_b + (size_t)l * EMB;

        ln_kernel<<<MROWS, blk256, 0, stream>>>(x, ln1_g + l * EMB, ln1_b + l * EMB, h);

        dim3 gqkv((3 * EMB + 63) / 64, MROWS / 64);
        gemm_kernel<false, false><<<gqkv, blk256, 0, stream>>>(h, aw, ab, nullptr, qkv, MROWS, 3 * EMB, EMB);

        dim3 gattn(TSEQ, NH, NB);
        attn_kernel<<<gattn, dim3(64), 0, stream>>>(qkv, y);

        dim3 gproj((EMB + 63) / 64, MROWS / 64);
        gemm_kernel<false, false><<<gproj, blk256, 0, stream>>>(y, pw, pb, x, x, MROWS, EMB, EMB);

        ln_kernel<<<MROWS, blk256, 0, stream>>>(x, ln2_g + l * EMB, ln2_b + l * EMB, h);

        dim3 gfc((4 * EMB + 63) / 64, MROWS / 64);
        gemm_kernel<false, true><<<gfc, blk256, 0, stream>>>(h, fw, fb, nullptr, g, MROWS, 4 * EMB, EMB);

        dim3 gmp((EMB + 63) / 64, MROWS / 64);
        gemm_kernel<false, false><<<gmp, blk256, 0, stream>>>(g, mw, mb, x, x, MROWS, EMB, 4 * EMB);
    }

    ln_kernel<<<MROWS, blk256, 0, stream>>>(x, lnf_g, lnf_b, h);

    dim3 ghead((VSZ + 63) / 64, MROWS / 64);
    gemm_kernel<true, false><<<ghead, blk256, 0, stream>>>(h, wte, nullptr, nullptr, out, MROWS, VSZ, EMB);
}

// Round 2
// 15192.020 us; speedup vs baseline: 2.5583x; 2.5583x over previous
//
#include <hip/hip_runtime.h>
#include <hip/hip_bf16.h>
#include <math.h>

#define VSZ 50257
#define VPAD 50304          // VSZ padded to multiple of 128
#define NLAYER 12
#define NH 12
#define EMB 768
#define TSEQ 1024
#define NB 4
#define MROWS (NB * TSEQ)   // 4096
#define DHEAD 64
#define LN_EPS 1e-5f

typedef __attribute__((ext_vector_type(8))) short bf16x8;
typedef __attribute__((ext_vector_type(4))) float f32x4;

__device__ __forceinline__ void load_lds16(const void* g, void* l) {
    __builtin_amdgcn_global_load_lds((const __attribute__((address_space(1))) unsigned int*)g,
                                     (__attribute__((address_space(3))) unsigned int*)l,
                                     16, 0, 0);
}

// ---------------- embedding ----------------
__global__ void embed_kernel(const int* __restrict__ idx, const float* __restrict__ wte,
                             const float* __restrict__ wpe, float* __restrict__ x) {
    int row = blockIdx.x;
    int t = row & (TSEQ - 1);
    int tok = idx[row];
    const float* wt = wte + (size_t)tok * EMB;
    const float* wp = wpe + (size_t)t * EMB;
    float* xo = x + (size_t)row * EMB;
    for (int e = threadIdx.x; e < EMB; e += blockDim.x)
        xo[e] = wt[e] + wp[e];
}

// ---------------- layernorm: fp32 in -> bf16 out ----------------
__global__ void ln_kernel(const float* __restrict__ x, const float* __restrict__ g,
                          const float* __restrict__ b, __hip_bfloat16* __restrict__ out) {
    int row = blockIdx.x;
    const float* xr = x + (size_t)row * EMB;
    __hip_bfloat16* yr = out + (size_t)row * EMB;
    int tid = threadIdx.x;
    float v0 = xr[tid], v1 = xr[tid + 256], v2 = xr[tid + 512];
    float s = v0 + v1 + v2;
    float ss = v0 * v0 + v1 * v1 + v2 * v2;
    #pragma unroll
    for (int i = 1; i < 64; i <<= 1) {
        s  += __shfl_xor(s, i, 64);
        ss += __shfl_xor(ss, i, 64);
    }
    __shared__ float sm[4], sv[4];
    int lane = tid & 63, wid = tid >> 6;
    if (lane == 0) { sm[wid] = s; sv[wid] = ss; }
    __syncthreads();
    float sum = sm[0] + sm[1] + sm[2] + sm[3];
    float sqs = sv[0] + sv[1] + sv[2] + sv[3];
    float mean = sum * (1.0f / EMB);
    float var = sqs * (1.0f / EMB) - mean * mean;
    float rstd = rsqrtf(var + LN_EPS);
    yr[tid]       = __float2bfloat16((v0 - mean) * rstd * g[tid]       + b[tid]);
    yr[tid + 256] = __float2bfloat16((v1 - mean) * rstd * g[tid + 256] + b[tid + 256]);
    yr[tid + 512] = __float2bfloat16((v2 - mean) * rstd * g[tid + 512] + b[tid + 512]);
}

// ---------------- weight convert+transpose: W[K,N] fp32 -> Wt[N,K] bf16 ----------------
// K, N multiples of 32. 256 threads = 32x8.
__global__ void convT_kernel(const float* __restrict__ W, __hip_bfloat16* __restrict__ Wt,
                             int K, int N) {
    __shared__ float tile[32][33];
    int n0 = blockIdx.x * 32, k0 = blockIdx.y * 32;
    int tx = threadIdx.x & 31, ty = threadIdx.x >> 5;
    #pragma unroll
    for (int i = ty; i < 32; i += 8)
        tile[i][tx] = W[(size_t)(k0 + i) * N + n0 + tx];
    __syncthreads();
    #pragma unroll
    for (int i = ty; i < 32; i += 8)
        Wt[(size_t)(n0 + i) * K + k0 + tx] = __float2bfloat16(tile[tx][i]);
}

// ---------------- wte convert + zero-pad rows: [V,E] fp32 -> [VPAD,E] bf16 ----------------
__global__ void conv_wte_kernel(const float* __restrict__ wte, __hip_bfloat16* __restrict__ o) {
    int row = blockIdx.x;
    bool pad = row >= VSZ;
    const float* src = wte + (size_t)row * EMB;
    __hip_bfloat16* dst = o + (size_t)row * EMB;
    for (int e = threadIdx.x; e < EMB; e += blockDim.x)
        dst[e] = __float2bfloat16(pad ? 0.0f : src[e]);
}

// ---------------- bf16 MFMA GEMM (m97 structure): C = act(A @ B^T + bias) [+ res] ----------------
// A: [M,K] bf16 row-major. B: [Npad,K] bf16 row-major (i.e. B^T of logical [K,N]).
// C row stride = ldc. Write guarded to col < Nclip. 128x128 tile, BK=32, 4 waves.
template <bool GELU, bool RES, bool OUTBF>
__global__ void gemm_bt(const __hip_bfloat16* __restrict__ A, const __hip_bfloat16* __restrict__ B,
                        const float* __restrict__ bias, const float* __restrict__ res,
                        float* __restrict__ Cf, __hip_bfloat16* __restrict__ Cb,
                        int M, int K, int ldc, int Nclip) {
    __shared__ __hip_bfloat16 Ash[128 * 32];
    __shared__ __hip_bfloat16 Bsh[128 * 32];
    const int tid = threadIdx.x;
    const int lane = tid & 63, wid = tid >> 6;
    const int wr = wid >> 1, wc = wid & 1;
    const int m0 = blockIdx.y * 128, n0 = blockIdx.x * 128;

    f32x4 acc[4][4] = {};

    const int srow = lane >> 2;          // 0..15
    const int scol = (lane & 3) * 8;     // element col within 32

    for (int k0 = 0; k0 < K; k0 += 32) {
        #pragma unroll
        for (int it = 0; it < 2; ++it) {
            int c = wid + it * 4;        // chunk 0..7, wave-uniform
            const __hip_bfloat16* ga = A + (size_t)(m0 + c * 16 + srow) * K + k0 + scol;
            load_lds16(ga, &Ash[c * 512]);
            const __hip_bfloat16* gb = B + (size_t)(n0 + c * 16 + srow) * K + k0 + scol;
            load_lds16(gb, &Bsh[c * 512]);
        }
        __syncthreads();   // drains vmcnt before barrier (compiler-inserted)
        bf16x8 a[4], b[4];
        #pragma unroll
        for (int m = 0; m < 4; ++m)
            a[m] = *(const bf16x8*)&Ash[(wr * 64 + m * 16 + (lane & 15)) * 32 + (lane >> 4) * 8];
        #pragma unroll
        for (int n = 0; n < 4; ++n)
            b[n] = *(const bf16x8*)&Bsh[(wc * 64 + n * 16 + (lane & 15)) * 32 + (lane >> 4) * 8];
        #pragma unroll
        for (int m = 0; m < 4; ++m)
            #pragma unroll
            for (int n = 0; n < 4; ++n)
                acc[m][n] = __builtin_amdgcn_mfma_f32_16x16x32_bf16(a[m], b[n], acc[m][n], 0, 0, 0);
        __syncthreads();
    }

    const int crow0 = m0 + wr * 64, ccol0 = n0 + wc * 64;
    #pragma unroll
    for (int m = 0; m < 4; ++m) {
        #pragma unroll
        for (int n = 0; n < 4; ++n) {
            int col = ccol0 + n * 16 + (lane & 15);
            if (col >= Nclip) continue;
            float bv = bias ? bias[col] : 0.0f;
            #pragma unroll
            for (int j = 0; j < 4; ++j) {
                int r = crow0 + m * 16 + (lane >> 4) * 4 + j;
                float v = acc[m][n][j] + bv;
                if (GELU) {
                    float t = 0.7978845608028654f * (v + 0.044715f * v * v * v);
                    v = 0.5f * v * (1.0f + tanhf(t));
                }
                if (RES) v += res[(size_t)r * ldc + col];
                if (OUTBF) Cb[(size_t)r * ldc + col] = __float2bfloat16(v);
                else       Cf[(size_t)r * ldc + col] = v;
            }
        }
    }
}

// ---------------- causal attention, one wave per (q, h, b); fp32 in, bf16 out ----------------
__global__ void attn_kernel(const float* __restrict__ qkv, __hip_bfloat16* __restrict__ y) {
    int q = blockIdx.x;
    int h = blockIdx.y;
    int b = blockIdx.z;
    int tid = threadIdx.x;  // 0..63
    __shared__ float qs[DHEAD];
    __shared__ float p[TSEQ];

    const size_t rowstride = 3 * EMB;
    const float* qrow = qkv + ((size_t)(b * TSEQ + q)) * rowstride + h * DHEAD;
    qs[tid] = qrow[tid];
    __syncthreads();

    float mloc = -INFINITY;
    for (int k = tid; k <= q; k += 64) {
        const float* krow = qkv + ((size_t)(b * TSEQ + k)) * rowstride + EMB + h * DHEAD;
        float s = 0.0f;
        #pragma unroll
        for (int d = 0; d < DHEAD; d++) s += qs[d] * krow[d];
        s *= 0.125f;
        p[k] = s;
        mloc = fmaxf(mloc, s);
    }
    #pragma unroll
    for (int i = 1; i < 64; i <<= 1) mloc = fmaxf(mloc, __shfl_xor(mloc, i, 64));
    float sloc = 0.0f;
    for (int k = tid; k <= q; k += 64) {
        float e = expf(p[k] - mloc);
        p[k] = e;
        sloc += e;
    }
    #pragma unroll
    for (int i = 1; i < 64; i <<= 1) sloc += __shfl_xor(sloc, i, 64);
    float inv = 1.0f / sloc;
    __syncthreads();
    const float* vbase = qkv + (size_t)b * TSEQ * rowstride + 2 * EMB + h * DHEAD + tid;
    float acc = 0.0f;
    for (int k = 0; k <= q; k++) acc += p[k] * vbase[(size_t)k * rowstride];
    y[((size_t)(b * TSEQ + q)) * EMB + h * DHEAD + tid] = __float2bfloat16(acc * inv);
}

// ---------------- launcher ----------------
extern "C" void kernel_launch(void* const* d_in, const int* in_sizes, int n_in,
                              void* d_out, int out_size, void* d_ws, size_t ws_size,
                              hipStream_t stream) {
    const int*   idx     = (const int*)d_in[0];
    const float* wte     = (const float*)d_in[1];
    const float* wpe     = (const float*)d_in[2];
    const float* ln1_g   = (const float*)d_in[3];
    const float* ln1_b   = (const float*)d_in[4];
    const float* attn_w  = (const float*)d_in[5];
    const float* attn_b  = (const float*)d_in[6];
    const float* proj_w  = (const float*)d_in[7];
    const float* proj_b  = (const float*)d_in[8];
    const float* ln2_g   = (const float*)d_in[9];
    const float* ln2_b   = (const float*)d_in[10];
    const float* fc_w    = (const float*)d_in[11];
    const float* fc_b    = (const float*)d_in[12];
    const float* mproj_w = (const float*)d_in[13];
    const float* mproj_b = (const float*)d_in[14];
    const float* lnf_g   = (const float*)d_in[15];
    const float* lnf_b   = (const float*)d_in[16];
    float* out = (float*)d_out;

    // ---- workspace carve-up (bytes) ----
    char* w = (char*)d_ws;
    float* x = (float*)w;                 w += (size_t)MROWS * EMB * 4;        // 12.6 MB
    float* qkv = (float*)w;               w += (size_t)MROWS * 3 * EMB * 4;    // 37.7 MB
    __hip_bfloat16* h = (__hip_bfloat16*)w;   w += (size_t)MROWS * EMB * 2;    // 6.3 MB
    __hip_bfloat16* y = (__hip_bfloat16*)w;   w += (size_t)MROWS * EMB * 2;    // 6.3 MB
    __hip_bfloat16* g = (__hip_bfloat16*)w;   w += (size_t)MROWS * 4 * EMB * 2;// 25.2 MB
    __hip_bfloat16* wqkvT = (__hip_bfloat16*)w;   w += (size_t)3 * EMB * EMB * 2;   // 3.5 MB
    __hip_bfloat16* wprojT = (__hip_bfloat16*)w;  w += (size_t)EMB * EMB * 2;       // 1.2 MB
    __hip_bfloat16* wfcT = (__hip_bfloat16*)w;    w += (size_t)4 * EMB * EMB * 2;   // 4.7 MB
    __hip_bfloat16* wmprojT = (__hip_bfloat16*)w; w += (size_t)4 * EMB * EMB * 2;   // 4.7 MB
    __hip_bfloat16* wteB = (__hip_bfloat16*)w;    w += (size_t)VPAD * EMB * 2;      // 77.3 MB

    dim3 blk256(256);

    embed_kernel<<<MROWS, blk256, 0, stream>>>(idx, wte, wpe, x);
    conv_wte_kernel<<<VPAD, blk256, 0, stream>>>(wte, wteB);

    for (int l = 0; l < NLAYER; l++) {
        const float* aw = attn_w + (size_t)l * EMB * 3 * EMB;
        const float* ab = attn_b + (size_t)l * 3 * EMB;
        const float* pw = proj_w + (size_t)l * EMB * EMB;
        const float* pb = proj_b + (size_t)l * EMB;
        const float* fw = fc_w   + (size_t)l * EMB * 4 * EMB;
        const float* fb = fc_b   + (size_t)l * 4 * EMB;
        const float* mw = mproj_w + (size_t)l * 4 * EMB * EMB;
        const float* mb = mproj_b + (size_t)l * EMB;

        ln_kernel<<<MROWS, blk256, 0, stream>>>(x, ln1_g + l * EMB, ln1_b + l * EMB, h);

        convT_kernel<<<dim3(3 * EMB / 32, EMB / 32), blk256, 0, stream>>>(aw, wqkvT, EMB, 3 * EMB);
        gemm_bt<false, false, false><<<dim3(3 * EMB / 128, MROWS / 128), blk256, 0, stream>>>(
            h, wqkvT, ab, nullptr, qkv, nullptr, MROWS, EMB, 3 * EMB, 3 * EMB);

        attn_kernel<<<dim3(TSEQ, NH, NB), dim3(64), 0, stream>>>(qkv, y);

        convT_kernel<<<dim3(EMB / 32, EMB / 32), blk256, 0, stream>>>(pw, wprojT, EMB, EMB);
        gemm_bt<false, true, false><<<dim3(EMB / 128, MROWS / 128), blk256, 0, stream>>>(
            y, wprojT, pb, x, x, nullptr, MROWS, EMB, EMB, EMB);

        ln_kernel<<<MROWS, blk256, 0, stream>>>(x, ln2_g + l * EMB, ln2_b + l * EMB, h);

        convT_kernel<<<dim3(4 * EMB / 32, EMB / 32), blk256, 0, stream>>>(fw, wfcT, EMB, 4 * EMB);
        gemm_bt<true, false, true><<<dim3(4 * EMB / 128, MROWS / 128), blk256, 0, stream>>>(
            h, wfcT, fb, nullptr, nullptr, g, MROWS, EMB, 4 * EMB, 4 * EMB);

        convT_kernel<<<dim3(EMB / 32, 4 * EMB / 32), blk256, 0, stream>>>(mw, wmprojT, 4 * EMB, EMB);
        gemm_bt<false, true, false><<<dim3(EMB / 128, MROWS / 128), blk256, 0, stream>>>(
            g, wmprojT, mb, x, x, nullptr, MROWS, 4 * EMB, EMB, EMB);
    }

    ln_kernel<<<MROWS, blk256, 0, stream>>>(x, lnf_g, lnf_b, h);

    gemm_bt<false, false, false><<<dim3(VPAD / 128, MROWS / 128), blk256, 0, stream>>>(
        h, wteB, nullptr, nullptr, out, nullptr, MROWS, EMB, VSZ, VSZ);
}

// Round 3
// 3794.608 us; speedup vs baseline: 10.2425x; 4.0036x over previous
//
#include <hip/hip_runtime.h>
#include <hip/hip_bf16.h>
#include <math.h>

#define VSZ 50257
#define VPAD 50304
#define NLAYER 12
#define NH 12
#define EMB 768
#define TSEQ 1024
#define NB 4
#define MROWS (NB * TSEQ)   // 4096
#define DHEAD 64
#define LN_EPS 1e-5f

typedef __attribute__((ext_vector_type(8))) short bf16x8;
typedef __attribute__((ext_vector_type(4))) float f32x4;

__device__ __forceinline__ void load_lds16(const void* g, void* l) {
    __builtin_amdgcn_global_load_lds((const __attribute__((address_space(1))) unsigned int*)g,
                                     (__attribute__((address_space(3))) unsigned int*)l,
                                     16, 0, 0);
}

// ---------------- embedding ----------------
__global__ void embed_kernel(const int* __restrict__ idx, const float* __restrict__ wte,
                             const float* __restrict__ wpe, float* __restrict__ x) {
    int row = blockIdx.x;
    int t = row & (TSEQ - 1);
    int tok = idx[row];
    const float* wt = wte + (size_t)tok * EMB;
    const float* wp = wpe + (size_t)t * EMB;
    float* xo = x + (size_t)row * EMB;
    for (int e = threadIdx.x; e < EMB; e += blockDim.x)
        xo[e] = wt[e] + wp[e];
}

// ---------------- layernorm: fp32 in -> bf16 out ----------------
__global__ void ln_kernel(const float* __restrict__ x, const float* __restrict__ g,
                          const float* __restrict__ b, __hip_bfloat16* __restrict__ out) {
    int row = blockIdx.x;
    const float* xr = x + (size_t)row * EMB;
    __hip_bfloat16* yr = out + (size_t)row * EMB;
    int tid = threadIdx.x;
    float v0 = xr[tid], v1 = xr[tid + 256], v2 = xr[tid + 512];
    float s = v0 + v1 + v2;
    float ss = v0 * v0 + v1 * v1 + v2 * v2;
    #pragma unroll
    for (int i = 1; i < 64; i <<= 1) {
        s  += __shfl_xor(s, i, 64);
        ss += __shfl_xor(ss, i, 64);
    }
    __shared__ float sm[4], sv[4];
    int lane = tid & 63, wid = tid >> 6;
    if (lane == 0) { sm[wid] = s; sv[wid] = ss; }
    __syncthreads();
    float sum = sm[0] + sm[1] + sm[2] + sm[3];
    float sqs = sv[0] + sv[1] + sv[2] + sv[3];
    float mean = sum * (1.0f / EMB);
    float var = sqs * (1.0f / EMB) - mean * mean;
    float rstd = rsqrtf(var + LN_EPS);
    yr[tid]       = __float2bfloat16((v0 - mean) * rstd * g[tid]       + b[tid]);
    yr[tid + 256] = __float2bfloat16((v1 - mean) * rstd * g[tid + 256] + b[tid + 256]);
    yr[tid + 512] = __float2bfloat16((v2 - mean) * rstd * g[tid + 512] + b[tid + 512]);
}

// ---------------- weight convert+transpose: W[K,N] fp32 -> Wt[N,K] bf16 ----------------
__global__ void convT_kernel(const float* __restrict__ W, __hip_bfloat16* __restrict__ Wt,
                             int K, int N) {
    __shared__ float tile[32][33];
    int n0 = blockIdx.x * 32, k0 = blockIdx.y * 32;
    int tx = threadIdx.x & 31, ty = threadIdx.x >> 5;
    #pragma unroll
    for (int i = ty; i < 32; i += 8)
        tile[i][tx] = W[(size_t)(k0 + i) * N + n0 + tx];
    __syncthreads();
    #pragma unroll
    for (int i = ty; i < 32; i += 8)
        Wt[(size_t)(n0 + i) * K + k0 + tx] = __float2bfloat16(tile[tx][i]);
}

// ---------------- wte convert + pad ----------------
__global__ void conv_wte_kernel(const float* __restrict__ wte, __hip_bfloat16* __restrict__ o) {
    int row = blockIdx.x;
    bool pad = row >= VSZ;
    const float* src = wte + (size_t)row * EMB;
    __hip_bfloat16* dst = o + (size_t)row * EMB;
    for (int e = threadIdx.x; e < EMB; e += blockDim.x)
        dst[e] = __float2bfloat16(pad ? 0.0f : src[e]);
}

// ---------------- bf16 MFMA GEMM: C = act(A @ B^T + bias) [+ res] ----------------
// OUT: 0=fp32 Cf, 1=bf16 Cb, 2=qkv-split (cols<1536 -> Cb[r*1536+col], else vT transposed)
template <bool GELU, bool RES, int OUT>
__global__ void gemm_bt(const __hip_bfloat16* __restrict__ A, const __hip_bfloat16* __restrict__ B,
                        const float* __restrict__ bias, const float* __restrict__ res,
                        float* __restrict__ Cf, __hip_bfloat16* __restrict__ Cb,
                        __hip_bfloat16* __restrict__ vt,
                        int M, int K, int ldc, int Nclip) {
    __shared__ __hip_bfloat16 Ash[128 * 32];
    __shared__ __hip_bfloat16 Bsh[128 * 32];
    const int tid = threadIdx.x;
    const int lane = tid & 63, wid = tid >> 6;
    const int wr = wid >> 1, wc = wid & 1;
    const int m0 = blockIdx.y * 128, n0 = blockIdx.x * 128;

    f32x4 acc[4][4] = {};
    const int srow = lane >> 2;
    const int scol = (lane & 3) * 8;

    for (int k0 = 0; k0 < K; k0 += 32) {
        #pragma unroll
        for (int it = 0; it < 2; ++it) {
            int c = wid + it * 4;
            const __hip_bfloat16* ga = A + (size_t)(m0 + c * 16 + srow) * K + k0 + scol;
            load_lds16(ga, &Ash[c * 512]);
            const __hip_bfloat16* gb = B + (size_t)(n0 + c * 16 + srow) * K + k0 + scol;
            load_lds16(gb, &Bsh[c * 512]);
        }
        __syncthreads();
        bf16x8 a[4], b[4];
        #pragma unroll
        for (int m = 0; m < 4; ++m)
            a[m] = *(const bf16x8*)&Ash[(wr * 64 + m * 16 + (lane & 15)) * 32 + (lane >> 4) * 8];
        #pragma unroll
        for (int n = 0; n < 4; ++n)
            b[n] = *(const bf16x8*)&Bsh[(wc * 64 + n * 16 + (lane & 15)) * 32 + (lane >> 4) * 8];
        #pragma unroll
        for (int m = 0; m < 4; ++m)
            #pragma unroll
            for (int n = 0; n < 4; ++n)
                acc[m][n] = __builtin_amdgcn_mfma_f32_16x16x32_bf16(a[m], b[n], acc[m][n], 0, 0, 0);
        __syncthreads();
    }

    const int crow0 = m0 + wr * 64, ccol0 = n0 + wc * 64;
    #pragma unroll
    for (int m = 0; m < 4; ++m) {
        #pragma unroll
        for (int n = 0; n < 4; ++n) {
            int col = ccol0 + n * 16 + (lane & 15);
            if (col >= Nclip) continue;
            float bv = bias ? bias[col] : 0.0f;
            #pragma unroll
            for (int j = 0; j < 4; ++j) {
                int r = crow0 + m * 16 + (lane >> 4) * 4 + j;
                float v = acc[m][n][j] + bv;
                if (GELU) {
                    float t = 0.7978845608028654f * (v + 0.044715f * v * v * v);
                    v = 0.5f * v * (1.0f + tanhf(t));
                }
                if (RES) v += res[(size_t)r * ldc + col];
                if (OUT == 0) Cf[(size_t)r * ldc + col] = v;
                else if (OUT == 1) Cb[(size_t)r * ldc + col] = __float2bfloat16(v);
                else {
                    if (col < 2 * EMB) Cb[(size_t)r * (2 * EMB) + col] = __float2bfloat16(v);
                    else {
                        int hh = (col - 2 * EMB) >> 6, dd = (col - 2 * EMB) & 63;
                        int bb = r >> 10, tt = r & 1023;
                        vt[(((size_t)bb * NH + hh) * 64 + dd) * TSEQ + tt] = __float2bfloat16(v);
                    }
                }
            }
        }
    }
}

// ---------------- MFMA flash attention ----------------
// qk: [B*T][1536] bf16 (Q cols 0..767, K cols 768..1535). vT: [B*H][64][T] bf16.
// y: [B*T][768] bf16. Grid (T/64, H, B), 256 threads (4 waves x 16 q-rows).
__global__ __launch_bounds__(256) void flash_attn(const __hip_bfloat16* __restrict__ qk,
                                                  const __hip_bfloat16* __restrict__ vT,
                                                  __hip_bfloat16* __restrict__ y) {
    const int qt = blockIdx.x, h = blockIdx.y, b = blockIdx.z;
    const int tid = threadIdx.x;
    const int lane = tid & 63, w = tid >> 6;
    const int g = lane >> 4, lr = lane & 15;

    __shared__ char KshB[64 * 128];      // [k][d] bf16, XOR-swizzled
    __shared__ char VshB[64 * 128];      // [d][k] bf16, XOR-swizzled
    __shared__ char PshB[4][16 * 128];   // per-wave P [q][k] bf16, XOR-swizzled

    // Q fragments in registers: row = lr, d-slice = g*8 (+0 / +32)
    const __hip_bfloat16* qrow = qk + ((size_t)(b * TSEQ + qt * 64 + w * 16 + lr)) * 1536 + h * 64;
    bf16x8 qf0 = *(const bf16x8*)(qrow + g * 8);
    bf16x8 qf1 = *(const bf16x8*)(qrow + 32 + g * 8);

    float m[4], l[4];
    f32x4 o[4];
    #pragma unroll
    for (int j = 0; j < 4; ++j) { m[j] = -1e30f; l[j] = 0.0f; }
    #pragma unroll
    for (int n = 0; n < 4; ++n) o[n] = (f32x4){0.f, 0.f, 0.f, 0.f};

    const int r0 = tid >> 3;          // staging row 0..31
    const int c0 = (tid & 7) * 8;     // staging col (bf16 elems)

    for (int kt = 0; kt <= qt; ++kt) {
        __syncthreads();
        #pragma unroll
        for (int it = 0; it < 2; ++it) {
            int r = r0 + it * 32;
            bf16x8 kv = *(const bf16x8*)(qk + ((size_t)(b * TSEQ + kt * 64 + r)) * 1536 + EMB + h * 64 + c0);
            *(bf16x8*)(KshB + ((r * 128 + c0 * 2) ^ ((r & 7) << 4))) = kv;
            bf16x8 vv = *(const bf16x8*)(vT + (((size_t)(b * NH + h)) * 64 + r) * TSEQ + kt * 64 + c0);
            *(bf16x8*)(VshB + ((r * 128 + c0 * 2) ^ ((r & 7) << 4))) = vv;
        }
        __syncthreads();

        // QK^T: s[q 16][k 64] per wave
        f32x4 s[4] = {};
        #pragma unroll
        for (int n = 0; n < 4; ++n) {
            int kr = n * 16 + lr;
            bf16x8 kb0 = *(const bf16x8*)(KshB + ((kr * 128 + g * 16) ^ ((kr & 7) << 4)));
            bf16x8 kb1 = *(const bf16x8*)(KshB + ((kr * 128 + 64 + g * 16) ^ ((kr & 7) << 4)));
            s[n] = __builtin_amdgcn_mfma_f32_16x16x32_bf16(qf0, kb0, s[n], 0, 0, 0);
            s[n] = __builtin_amdgcn_mfma_f32_16x16x32_bf16(qf1, kb1, s[n], 0, 0, 0);
        }

        const bool diag = (kt == qt);
        float tmax[4] = {-1e30f, -1e30f, -1e30f, -1e30f};
        #pragma unroll
        for (int n = 0; n < 4; ++n)
            #pragma unroll
            for (int j = 0; j < 4; ++j) {
                float v = s[n][j] * 0.125f;
                if (diag && (n * 16 + lr > w * 16 + g * 4 + j)) v = -1e30f;
                s[n][j] = v;
                tmax[j] = fmaxf(tmax[j], v);
            }
        #pragma unroll
        for (int j = 0; j < 4; ++j)
            #pragma unroll
            for (int i = 1; i < 16; i <<= 1)
                tmax[j] = fmaxf(tmax[j], __shfl_xor(tmax[j], i, 64));

        float lsum[4] = {0.f, 0.f, 0.f, 0.f};
        float pexp[4][4];
        #pragma unroll
        for (int j = 0; j < 4; ++j) {
            float mn = fmaxf(m[j], tmax[j]);
            float sc = __expf(m[j] - mn);
            l[j] *= sc;
            m[j] = mn;
            #pragma unroll
            for (int n = 0; n < 4; ++n) {
                float p = __expf(s[n][j] - mn);
                pexp[n][j] = p;
                lsum[j] += p;
                o[n][j] *= sc;
            }
        }
        #pragma unroll
        for (int j = 0; j < 4; ++j) {
            #pragma unroll
            for (int i = 1; i < 16; i <<= 1) lsum[j] += __shfl_xor(lsum[j], i, 64);
            l[j] += lsum[j];
        }

        // P -> LDS (per-wave), then PV
        char* P = PshB[w];
        #pragma unroll
        for (int n = 0; n < 4; ++n)
            #pragma unroll
            for (int j = 0; j < 4; ++j) {
                int rw = g * 4 + j;
                *(__hip_bfloat16*)(P + ((rw * 128 + (n * 16 + lr) * 2) ^ ((rw & 7) << 4))) =
                    __float2bfloat16(pexp[n][j]);
            }
        asm volatile("s_waitcnt lgkmcnt(0)" ::: "memory");
        bf16x8 pa0 = *(const bf16x8*)(P + ((lr * 128 + g * 16) ^ ((lr & 7) << 4)));
        bf16x8 pa1 = *(const bf16x8*)(P + ((lr * 128 + 64 + g * 16) ^ ((lr & 7) << 4)));
        #pragma unroll
        for (int n = 0; n < 4; ++n) {
            int vr = n * 16 + lr;
            bf16x8 vb0 = *(const bf16x8*)(VshB + ((vr * 128 + g * 16) ^ ((vr & 7) << 4)));
            bf16x8 vb1 = *(const bf16x8*)(VshB + ((vr * 128 + 64 + g * 16) ^ ((vr & 7) << 4)));
            o[n] = __builtin_amdgcn_mfma_f32_16x16x32_bf16(pa0, vb0, o[n], 0, 0, 0);
            o[n] = __builtin_amdgcn_mfma_f32_16x16x32_bf16(pa1, vb1, o[n], 0, 0, 0);
        }
    }

    #pragma unroll
    for (int j = 0; j < 4; ++j) {
        float inv = 1.0f / l[j];
        int row = b * TSEQ + qt * 64 + w * 16 + g * 4 + j;
        #pragma unroll
        for (int n = 0; n < 4; ++n)
            y[(size_t)row * EMB + h * 64 + n * 16 + lr] = __float2bfloat16(o[n][j] * inv);
    }
}

// ---------------- launcher ----------------
extern "C" void kernel_launch(void* const* d_in, const int* in_sizes, int n_in,
                              void* d_out, int out_size, void* d_ws, size_t ws_size,
                              hipStream_t stream) {
    const int*   idx     = (const int*)d_in[0];
    const float* wte     = (const float*)d_in[1];
    const float* wpe     = (const float*)d_in[2];
    const float* ln1_g   = (const float*)d_in[3];
    const float* ln1_b   = (const float*)d_in[4];
    const float* attn_w  = (const float*)d_in[5];
    const float* attn_b  = (const float*)d_in[6];
    const float* proj_w  = (const float*)d_in[7];
    const float* proj_b  = (const float*)d_in[8];
    const float* ln2_g   = (const float*)d_in[9];
    const float* ln2_b   = (const float*)d_in[10];
    const float* fc_w    = (const float*)d_in[11];
    const float* fc_b    = (const float*)d_in[12];
    const float* mproj_w = (const float*)d_in[13];
    const float* mproj_b = (const float*)d_in[14];
    const float* lnf_g   = (const float*)d_in[15];
    const float* lnf_b   = (const float*)d_in[16];
    float* out = (float*)d_out;

    char* w = (char*)d_ws;
    float* x = (float*)w;                      w += (size_t)MROWS * EMB * 4;       // 12.6 MB
    __hip_bfloat16* qkb = (__hip_bfloat16*)w;  w += (size_t)MROWS * 2 * EMB * 2;   // 12.6 MB
    __hip_bfloat16* vTb = (__hip_bfloat16*)w;  w += (size_t)NB * NH * 64 * TSEQ * 2; // 6.3 MB
    __hip_bfloat16* h = (__hip_bfloat16*)w;    w += (size_t)MROWS * EMB * 2;       // 6.3 MB
    __hip_bfloat16* y = (__hip_bfloat16*)w;    w += (size_t)MROWS * EMB * 2;       // 6.3 MB
    __hip_bfloat16* g = (__hip_bfloat16*)w;    w += (size_t)MROWS * 4 * EMB * 2;   // 25.2 MB
    __hip_bfloat16* wqkvT = (__hip_bfloat16*)w;   w += (size_t)3 * EMB * EMB * 2;
    __hip_bfloat16* wprojT = (__hip_bfloat16*)w;  w += (size_t)EMB * EMB * 2;
    __hip_bfloat16* wfcT = (__hip_bfloat16*)w;    w += (size_t)4 * EMB * EMB * 2;
    __hip_bfloat16* wmprojT = (__hip_bfloat16*)w; w += (size_t)4 * EMB * EMB * 2;
    __hip_bfloat16* wteB = (__hip_bfloat16*)w;    w += (size_t)VPAD * EMB * 2;     // 77.3 MB

    dim3 blk256(256);

    embed_kernel<<<MROWS, blk256, 0, stream>>>(idx, wte, wpe, x);
    conv_wte_kernel<<<VPAD, blk256, 0, stream>>>(wte, wteB);

    for (int l = 0; l < NLAYER; l++) {
        const float* aw = attn_w + (size_t)l * EMB * 3 * EMB;
        const float* ab = attn_b + (size_t)l * 3 * EMB;
        const float* pw = proj_w + (size_t)l * EMB * EMB;
        const float* pb = proj_b + (size_t)l * EMB;
        const float* fw = fc_w   + (size_t)l * EMB * 4 * EMB;
        const float* fb = fc_b   + (size_t)l * 4 * EMB;
        const float* mw = mproj_w + (size_t)l * 4 * EMB * EMB;
        const float* mb = mproj_b + (size_t)l * EMB;

        ln_kernel<<<MROWS, blk256, 0, stream>>>(x, ln1_g + l * EMB, ln1_b + l * EMB, h);

        convT_kernel<<<dim3(3 * EMB / 32, EMB / 32), blk256, 0, stream>>>(aw, wqkvT, EMB, 3 * EMB);
        gemm_bt<false, false, 2><<<dim3(3 * EMB / 128, MROWS / 128), blk256, 0, stream>>>(
            h, wqkvT, ab, nullptr, nullptr, qkb, vTb, MROWS, EMB, 3 * EMB, 3 * EMB);

        flash_attn<<<dim3(TSEQ / 64, NH, NB), blk256, 0, stream>>>(qkb, vTb, y);

        convT_kernel<<<dim3(EMB / 32, EMB / 32), blk256, 0, stream>>>(pw, wprojT, EMB, EMB);
        gemm_bt<false, true, 0><<<dim3(EMB / 128, MROWS / 128), blk256, 0, stream>>>(
            y, wprojT, pb, x, x, nullptr, nullptr, MROWS, EMB, EMB, EMB);

        ln_kernel<<<MROWS, blk256, 0, stream>>>(x, ln2_g + l * EMB, ln2_b + l * EMB, h);

        convT_kernel<<<dim3(4 * EMB / 32, EMB / 32), blk256, 0, stream>>>(fw, wfcT, EMB, 4 * EMB);
        gemm_bt<true, false, 1><<<dim3(4 * EMB / 128, MROWS / 128), blk256, 0, stream>>>(
            h, wfcT, fb, nullptr, nullptr, g, nullptr, MROWS, EMB, 4 * EMB, 4 * EMB);

        convT_kernel<<<dim3(EMB / 32, 4 * EMB / 32), blk256, 0, stream>>>(mw, wmprojT, 4 * EMB, EMB);
        gemm_bt<false, true, 0><<<dim3(EMB / 128, MROWS / 128), blk256, 0, stream>>>(
            g, wmprojT, mb, x, x, nullptr, nullptr, MROWS, 4 * EMB, EMB, EMB);
    }

    ln_kernel<<<MROWS, blk256, 0, stream>>>(x, lnf_g, lnf_b, h);

    gemm_bt<false, false, 0><<<dim3(VPAD / 128, MROWS / 128), blk256, 0, stream>>>(
        h, wteB, nullptr, nullptr, out, nullptr, nullptr, MROWS, EMB, VSZ, VSZ);
}

// Round 4
// 3723.420 us; speedup vs baseline: 10.4384x; 1.0191x over previous
//
#include <hip/hip_runtime.h>
#include <hip/hip_bf16.h>
#include <math.h>

#define VSZ 50257
#define VPAD 50304
#define NLAYER 12
#define NH 12
#define EMB 768
#define TSEQ 1024
#define NB 4
#define MROWS (NB * TSEQ)   // 4096
#define DHEAD 64
#define LN_EPS 1e-5f

typedef __attribute__((ext_vector_type(8))) short bf16x8;
typedef __attribute__((ext_vector_type(4))) float f32x4;

__device__ __forceinline__ void load_lds16(const void* g, void* l) {
    __builtin_amdgcn_global_load_lds((const __attribute__((address_space(1))) unsigned int*)g,
                                     (__attribute__((address_space(3))) unsigned int*)l,
                                     16, 0, 0);
}

// ---------------- embedding ----------------
__global__ void embed_kernel(const int* __restrict__ idx, const float* __restrict__ wte,
                             const float* __restrict__ wpe, float* __restrict__ x) {
    int row = blockIdx.x;
    int t = row & (TSEQ - 1);
    int tok = idx[row];
    const float* wt = wte + (size_t)tok * EMB;
    const float* wp = wpe + (size_t)t * EMB;
    float* xo = x + (size_t)row * EMB;
    for (int e = threadIdx.x; e < EMB; e += blockDim.x)
        xo[e] = wt[e] + wp[e];
}

// ---------------- layernorm: fp32 in -> bf16 out ----------------
__global__ void ln_kernel(const float* __restrict__ x, const float* __restrict__ g,
                          const float* __restrict__ b, __hip_bfloat16* __restrict__ out) {
    int row = blockIdx.x;
    const float* xr = x + (size_t)row * EMB;
    __hip_bfloat16* yr = out + (size_t)row * EMB;
    int tid = threadIdx.x;
    float v0 = xr[tid], v1 = xr[tid + 256], v2 = xr[tid + 512];
    float s = v0 + v1 + v2;
    float ss = v0 * v0 + v1 * v1 + v2 * v2;
    #pragma unroll
    for (int i = 1; i < 64; i <<= 1) {
        s  += __shfl_xor(s, i, 64);
        ss += __shfl_xor(ss, i, 64);
    }
    __shared__ float sm[4], sv[4];
    int lane = tid & 63, wid = tid >> 6;
    if (lane == 0) { sm[wid] = s; sv[wid] = ss; }
    __syncthreads();
    float sum = sm[0] + sm[1] + sm[2] + sm[3];
    float sqs = sv[0] + sv[1] + sv[2] + sv[3];
    float mean = sum * (1.0f / EMB);
    float var = sqs * (1.0f / EMB) - mean * mean;
    float rstd = rsqrtf(var + LN_EPS);
    yr[tid]       = __float2bfloat16((v0 - mean) * rstd * g[tid]       + b[tid]);
    yr[tid + 256] = __float2bfloat16((v1 - mean) * rstd * g[tid + 256] + b[tid + 256]);
    yr[tid + 512] = __float2bfloat16((v2 - mean) * rstd * g[tid + 512] + b[tid + 512]);
}

// ---------------- fused per-layer weight transpose: 4 matrices in one launch ----------------
// W[K,N] fp32 -> Wt[N,K] bf16. Tile ranges: aw 0..1727, pw ..2303, fw ..4607, mw ..6911.
__global__ void convT4_kernel(const float* __restrict__ aw, const float* __restrict__ pw,
                              const float* __restrict__ fw, const float* __restrict__ mw,
                              __hip_bfloat16* __restrict__ awT, __hip_bfloat16* __restrict__ pwT,
                              __hip_bfloat16* __restrict__ fwT, __hip_bfloat16* __restrict__ mwT) {
    __shared__ float tile[32][33];
    int bid = blockIdx.x;
    const float* W; __hip_bfloat16* Wt; int K, N, t;
    if (bid < 1728)      { W = aw; Wt = awT; K = 768;  N = 2304; t = bid; }
    else if (bid < 2304) { W = pw; Wt = pwT; K = 768;  N = 768;  t = bid - 1728; }
    else if (bid < 4608) { W = fw; Wt = fwT; K = 768;  N = 3072; t = bid - 2304; }
    else                 { W = mw; Wt = mwT; K = 3072; N = 768;  t = bid - 4608; }
    int NT = N >> 5;
    int n0 = (t % NT) << 5, k0 = (t / NT) << 5;
    int tx = threadIdx.x & 31, ty = threadIdx.x >> 5;
    #pragma unroll
    for (int i = ty; i < 32; i += 8)
        tile[i][tx] = W[(size_t)(k0 + i) * N + n0 + tx];
    __syncthreads();
    #pragma unroll
    for (int i = ty; i < 32; i += 8)
        Wt[(size_t)(n0 + i) * K + k0 + tx] = __float2bfloat16(tile[tx][i]);
}

// ---------------- wte convert + pad ----------------
__global__ void conv_wte_kernel(const float* __restrict__ wte, __hip_bfloat16* __restrict__ o) {
    int row = blockIdx.x;
    bool pad = row >= VSZ;
    const float* src = wte + (size_t)row * EMB;
    __hip_bfloat16* dst = o + (size_t)row * EMB;
    for (int e = threadIdx.x; e < EMB; e += blockDim.x)
        dst[e] = __float2bfloat16(pad ? 0.0f : src[e]);
}

// ---------------- bf16 MFMA GEMM: C = act(A @ B^T + bias) [+ res] ----------------
// 1-D grid NT*32 blocks; XCD-swizzled, M-fastest so consecutive blocks on one XCD
// share the same 128-col B panel (L2-resident). M fixed = 4096 (MT=32).
// OUT: 0=fp32 Cf, 1=bf16 Cb, 2=qkv-split (cols<1536 -> Cb, else vT transposed)
template <bool GELU, bool RES, int OUT>
__global__ void gemm_bt(const __hip_bfloat16* __restrict__ A, const __hip_bfloat16* __restrict__ B,
                        const float* __restrict__ bias, const float* __restrict__ res,
                        float* __restrict__ Cf, __hip_bfloat16* __restrict__ Cb,
                        __hip_bfloat16* __restrict__ vt,
                        int K, int ldc, int Nclip) {
    __shared__ __hip_bfloat16 Ash[128 * 32];
    __shared__ __hip_bfloat16 Bsh[128 * 32];
    const int tid = threadIdx.x;
    const int lane = tid & 63, wid = tid >> 6;
    const int wr = wid >> 1, wc = wid & 1;

    // XCD-aware swizzle (nwg % 8 == 0 for all our launches) + M-fastest order
    const int nwg = gridDim.x;
    const int cpx = nwg >> 3;
    const int wg = (blockIdx.x & 7) * cpx + (blockIdx.x >> 3);
    const int m0 = (wg & 31) * 128;
    const int n0 = (wg >> 5) * 128;

    f32x4 acc[4][4] = {};
    const int srow = lane >> 2;
    const int scol = (lane & 3) * 8;

    for (int k0 = 0; k0 < K; k0 += 32) {
        #pragma unroll
        for (int it = 0; it < 2; ++it) {
            int c = wid + it * 4;
            const __hip_bfloat16* ga = A + (size_t)(m0 + c * 16 + srow) * K + k0 + scol;
            load_lds16(ga, &Ash[c * 512]);
            const __hip_bfloat16* gb = B + (size_t)(n0 + c * 16 + srow) * K + k0 + scol;
            load_lds16(gb, &Bsh[c * 512]);
        }
        __syncthreads();
        bf16x8 a[4], b[4];
        #pragma unroll
        for (int m = 0; m < 4; ++m)
            a[m] = *(const bf16x8*)&Ash[(wr * 64 + m * 16 + (lane & 15)) * 32 + (lane >> 4) * 8];
        #pragma unroll
        for (int n = 0; n < 4; ++n)
            b[n] = *(const bf16x8*)&Bsh[(wc * 64 + n * 16 + (lane & 15)) * 32 + (lane >> 4) * 8];
        #pragma unroll
        for (int m = 0; m < 4; ++m)
            #pragma unroll
            for (int n = 0; n < 4; ++n)
                acc[m][n] = __builtin_amdgcn_mfma_f32_16x16x32_bf16(a[m], b[n], acc[m][n], 0, 0, 0);
        __syncthreads();
    }

    const int crow0 = m0 + wr * 64, ccol0 = n0 + wc * 64;
    #pragma unroll
    for (int m = 0; m < 4; ++m) {
        #pragma unroll
        for (int n = 0; n < 4; ++n) {
            int col = ccol0 + n * 16 + (lane & 15);
            if (col >= Nclip) continue;
            float bv = bias ? bias[col] : 0.0f;
            #pragma unroll
            for (int j = 0; j < 4; ++j) {
                int r = crow0 + m * 16 + (lane >> 4) * 4 + j;
                float v = acc[m][n][j] + bv;
                if (GELU) {
                    float t = 0.7978845608028654f * (v + 0.044715f * v * v * v);
                    v = 0.5f * v * (1.0f + tanhf(t));
                }
                if (RES) v += res[(size_t)r * ldc + col];
                if (OUT == 0) Cf[(size_t)r * ldc + col] = v;
                else if (OUT == 1) Cb[(size_t)r * ldc + col] = __float2bfloat16(v);
                else {
                    if (col < 2 * EMB) Cb[(size_t)r * (2 * EMB) + col] = __float2bfloat16(v);
                    else {
                        int hh = (col - 2 * EMB) >> 6, dd = (col - 2 * EMB) & 63;
                        int bb = r >> 10, tt = r & 1023;
                        vt[(((size_t)bb * NH + hh) * 64 + dd) * TSEQ + tt] = __float2bfloat16(v);
                    }
                }
            }
        }
    }
}

// ---------------- MFMA flash attention ----------------
__global__ __launch_bounds__(256) void flash_attn(const __hip_bfloat16* __restrict__ qk,
                                                  const __hip_bfloat16* __restrict__ vT,
                                                  __hip_bfloat16* __restrict__ y) {
    const int qt = blockIdx.x, h = blockIdx.y, b = blockIdx.z;
    const int tid = threadIdx.x;
    const int lane = tid & 63, w = tid >> 6;
    const int g = lane >> 4, lr = lane & 15;

    __shared__ char KshB[64 * 128];      // [k][d] bf16, XOR-swizzled
    __shared__ char VshB[64 * 128];      // [d][k] bf16, XOR-swizzled
    __shared__ char PshB[4][16 * 128];   // per-wave P [q][k] bf16, XOR-swizzled

    const __hip_bfloat16* qrow = qk + ((size_t)(b * TSEQ + qt * 64 + w * 16 + lr)) * 1536 + h * 64;
    bf16x8 qf0 = *(const bf16x8*)(qrow + g * 8);
    bf16x8 qf1 = *(const bf16x8*)(qrow + 32 + g * 8);

    float m[4], l[4];
    f32x4 o[4];
    #pragma unroll
    for (int j = 0; j < 4; ++j) { m[j] = -1e30f; l[j] = 0.0f; }
    #pragma unroll
    for (int n = 0; n < 4; ++n) o[n] = (f32x4){0.f, 0.f, 0.f, 0.f};

    const int r0 = tid >> 3;
    const int c0 = (tid & 7) * 8;

    for (int kt = 0; kt <= qt; ++kt) {
        __syncthreads();
        #pragma unroll
        for (int it = 0; it < 2; ++it) {
            int r = r0 + it * 32;
            bf16x8 kv = *(const bf16x8*)(qk + ((size_t)(b * TSEQ + kt * 64 + r)) * 1536 + EMB + h * 64 + c0);
            *(bf16x8*)(KshB + ((r * 128 + c0 * 2) ^ ((r & 7) << 4))) = kv;
            bf16x8 vv = *(const bf16x8*)(vT + (((size_t)(b * NH + h)) * 64 + r) * TSEQ + kt * 64 + c0);
            *(bf16x8*)(VshB + ((r * 128 + c0 * 2) ^ ((r & 7) << 4))) = vv;
        }
        __syncthreads();

        f32x4 s[4] = {};
        #pragma unroll
        for (int n = 0; n < 4; ++n) {
            int kr = n * 16 + lr;
            bf16x8 kb0 = *(const bf16x8*)(KshB + ((kr * 128 + g * 16) ^ ((kr & 7) << 4)));
            bf16x8 kb1 = *(const bf16x8*)(KshB + ((kr * 128 + 64 + g * 16) ^ ((kr & 7) << 4)));
            s[n] = __builtin_amdgcn_mfma_f32_16x16x32_bf16(qf0, kb0, s[n], 0, 0, 0);
            s[n] = __builtin_amdgcn_mfma_f32_16x16x32_bf16(qf1, kb1, s[n], 0, 0, 0);
        }

        const bool diag = (kt == qt);
        float tmax[4] = {-1e30f, -1e30f, -1e30f, -1e30f};
        #pragma unroll
        for (int n = 0; n < 4; ++n)
            #pragma unroll
            for (int j = 0; j < 4; ++j) {
                float v = s[n][j] * 0.125f;
                if (diag && (n * 16 + lr > w * 16 + g * 4 + j)) v = -1e30f;
                s[n][j] = v;
                tmax[j] = fmaxf(tmax[j], v);
            }
        #pragma unroll
        for (int j = 0; j < 4; ++j)
            #pragma unroll
            for (int i = 1; i < 16; i <<= 1)
                tmax[j] = fmaxf(tmax[j], __shfl_xor(tmax[j], i, 64));

        float lsum[4] = {0.f, 0.f, 0.f, 0.f};
        float pexp[4][4];
        #pragma unroll
        for (int j = 0; j < 4; ++j) {
            float mn = fmaxf(m[j], tmax[j]);
            float sc = __expf(m[j] - mn);
            l[j] *= sc;
            m[j] = mn;
            #pragma unroll
            for (int n = 0; n < 4; ++n) {
                float p = __expf(s[n][j] - mn);
                pexp[n][j] = p;
                lsum[j] += p;
                o[n][j] *= sc;
            }
        }
        #pragma unroll
        for (int j = 0; j < 4; ++j) {
            #pragma unroll
            for (int i = 1; i < 16; i <<= 1) lsum[j] += __shfl_xor(lsum[j], i, 64);
            l[j] += lsum[j];
        }

        char* P = PshB[w];
        #pragma unroll
        for (int n = 0; n < 4; ++n)
            #pragma unroll
            for (int j = 0; j < 4; ++j) {
                int rw = g * 4 + j;
                *(__hip_bfloat16*)(P + ((rw * 128 + (n * 16 + lr) * 2) ^ ((rw & 7) << 4))) =
                    __float2bfloat16(pexp[n][j]);
            }
        asm volatile("s_waitcnt lgkmcnt(0)" ::: "memory");
        bf16x8 pa0 = *(const bf16x8*)(P + ((lr * 128 + g * 16) ^ ((lr & 7) << 4)));
        bf16x8 pa1 = *(const bf16x8*)(P + ((lr * 128 + 64 + g * 16) ^ ((lr & 7) << 4)));
        #pragma unroll
        for (int n = 0; n < 4; ++n) {
            int vr = n * 16 + lr;
            bf16x8 vb0 = *(const bf16x8*)(VshB + ((vr * 128 + g * 16) ^ ((vr & 7) << 4)));
            bf16x8 vb1 = *(const bf16x8*)(VshB + ((vr * 128 + 64 + g * 16) ^ ((vr & 7) << 4)));
            o[n] = __builtin_amdgcn_mfma_f32_16x16x32_bf16(pa0, vb0, o[n], 0, 0, 0);
            o[n] = __builtin_amdgcn_mfma_f32_16x16x32_bf16(pa1, vb1, o[n], 0, 0, 0);
        }
    }

    #pragma unroll
    for (int j = 0; j < 4; ++j) {
        float inv = 1.0f / l[j];
        int row = b * TSEQ + qt * 64 + w * 16 + g * 4 + j;
        #pragma unroll
        for (int n = 0; n < 4; ++n)
            y[(size_t)row * EMB + h * 64 + n * 16 + lr] = __float2bfloat16(o[n][j] * inv);
    }
}

// ---------------- launcher ----------------
extern "C" void kernel_launch(void* const* d_in, const int* in_sizes, int n_in,
                              void* d_out, int out_size, void* d_ws, size_t ws_size,
                              hipStream_t stream) {
    const int*   idx     = (const int*)d_in[0];
    const float* wte     = (const float*)d_in[1];
    const float* wpe     = (const float*)d_in[2];
    const float* ln1_g   = (const float*)d_in[3];
    const float* ln1_b   = (const float*)d_in[4];
    const float* attn_w  = (const float*)d_in[5];
    const float* attn_b  = (const float*)d_in[6];
    const float* proj_w  = (const float*)d_in[7];
    const float* proj_b  = (const float*)d_in[8];
    const float* ln2_g   = (const float*)d_in[9];
    const float* ln2_b   = (const float*)d_in[10];
    const float* fc_w    = (const float*)d_in[11];
    const float* fc_b    = (const float*)d_in[12];
    const float* mproj_w = (const float*)d_in[13];
    const float* mproj_b = (const float*)d_in[14];
    const float* lnf_g   = (const float*)d_in[15];
    const float* lnf_b   = (const float*)d_in[16];
    float* out = (float*)d_out;

    char* w = (char*)d_ws;
    float* x = (float*)w;                      w += (size_t)MROWS * EMB * 4;
    __hip_bfloat16* qkb = (__hip_bfloat16*)w;  w += (size_t)MROWS * 2 * EMB * 2;
    __hip_bfloat16* vTb = (__hip_bfloat16*)w;  w += (size_t)NB * NH * 64 * TSEQ * 2;
    __hip_bfloat16* h = (__hip_bfloat16*)w;    w += (size_t)MROWS * EMB * 2;
    __hip_bfloat16* y = (__hip_bfloat16*)w;    w += (size_t)MROWS * EMB * 2;
    __hip_bfloat16* g = (__hip_bfloat16*)w;    w += (size_t)MROWS * 4 * EMB * 2;
    __hip_bfloat16* wqkvT = (__hip_bfloat16*)w;   w += (size_t)3 * EMB * EMB * 2;
    __hip_bfloat16* wprojT = (__hip_bfloat16*)w;  w += (size_t)EMB * EMB * 2;
    __hip_bfloat16* wfcT = (__hip_bfloat16*)w;    w += (size_t)4 * EMB * EMB * 2;
    __hip_bfloat16* wmprojT = (__hip_bfloat16*)w; w += (size_t)4 * EMB * EMB * 2;
    __hip_bfloat16* wteB = (__hip_bfloat16*)w;    w += (size_t)VPAD * EMB * 2;

    dim3 blk256(256);

    embed_kernel<<<MROWS, blk256, 0, stream>>>(idx, wte, wpe, x);
    conv_wte_kernel<<<VPAD, blk256, 0, stream>>>(wte, wteB);

    for (int l = 0; l < NLAYER; l++) {
        const float* aw = attn_w + (size_t)l * EMB * 3 * EMB;
        const float* ab = attn_b + (size_t)l * 3 * EMB;
        const float* pw = proj_w + (size_t)l * EMB * EMB;
        const float* pb = proj_b + (size_t)l * EMB;
        const float* fw = fc_w   + (size_t)l * EMB * 4 * EMB;
        const float* fb = fc_b   + (size_t)l * 4 * EMB;
        const float* mw = mproj_w + (size_t)l * 4 * EMB * EMB;
        const float* mb = mproj_b + (size_t)l * EMB;

        ln_kernel<<<MROWS, blk256, 0, stream>>>(x, ln1_g + l * EMB, ln1_b + l * EMB, h);
        convT4_kernel<<<6912, blk256, 0, stream>>>(aw, pw, fw, mw, wqkvT, wprojT, wfcT, wmprojT);

        gemm_bt<false, false, 2><<<dim3((3 * EMB / 128) * 32), blk256, 0, stream>>>(
            h, wqkvT, ab, nullptr, nullptr, qkb, vTb, EMB, 3 * EMB, 3 * EMB);

        flash_attn<<<dim3(TSEQ / 64, NH, NB), blk256, 0, stream>>>(qkb, vTb, y);

        gemm_bt<false, true, 0><<<dim3((EMB / 128) * 32), blk256, 0, stream>>>(
            y, wprojT, pb, x, x, nullptr, nullptr, EMB, EMB, EMB);

        ln_kernel<<<MROWS, blk256, 0, stream>>>(x, ln2_g + l * EMB, ln2_b + l * EMB, h);

        gemm_bt<true, false, 1><<<dim3((4 * EMB / 128) * 32), blk256, 0, stream>>>(
            h, wfcT, fb, nullptr, nullptr, g, nullptr, EMB, 4 * EMB, 4 * EMB);

        gemm_bt<false, true, 0><<<dim3((EMB / 128) * 32), blk256, 0, stream>>>(
            g, wmprojT, mb, x, x, nullptr, nullptr, 4 * EMB, EMB, EMB);
    }

    ln_kernel<<<MROWS, blk256, 0, stream>>>(x, lnf_g, lnf_b, h);

    gemm_bt<false, false, 0><<<dim3((VPAD / 128) * 32), blk256, 0, stream>>>(
        h, wteB, nullptr, nullptr, out, nullptr, nullptr, EMB, VSZ, VSZ);
}

// Round 5
// 3509.949 us; speedup vs baseline: 11.0732x; 1.0608x over previous
//
#include <hip/hip_runtime.h>
#include <hip/hip_bf16.h>
#include <math.h>

#define VSZ 50257
#define VPAD 50304
#define NLAYER 12
#define NH 12
#define EMB 768
#define TSEQ 1024
#define NB 4
#define MROWS (NB * TSEQ)   // 4096
#define DHEAD 64
#define LN_EPS 1e-5f

typedef __attribute__((ext_vector_type(8))) short bf16x8;
typedef __attribute__((ext_vector_type(4))) float f32x4;

__device__ __forceinline__ void load_lds16(const void* g, void* l) {
    __builtin_amdgcn_global_load_lds((const __attribute__((address_space(1))) unsigned int*)g,
                                     (__attribute__((address_space(3))) unsigned int*)l,
                                     16, 0, 0);
}

// ---------------- embedding ----------------
__global__ void embed_kernel(const int* __restrict__ idx, const float* __restrict__ wte,
                             const float* __restrict__ wpe, float* __restrict__ x) {
    int row = blockIdx.x;
    int t = row & (TSEQ - 1);
    int tok = idx[row];
    const float* wt = wte + (size_t)tok * EMB;
    const float* wp = wpe + (size_t)t * EMB;
    float* xo = x + (size_t)row * EMB;
    for (int e = threadIdx.x; e < EMB; e += blockDim.x)
        xo[e] = wt[e] + wp[e];
}

// ---------------- layernorm: fp32 in -> bf16 out ----------------
__global__ void ln_kernel(const float* __restrict__ x, const float* __restrict__ g,
                          const float* __restrict__ b, __hip_bfloat16* __restrict__ out) {
    int row = blockIdx.x;
    const float* xr = x + (size_t)row * EMB;
    __hip_bfloat16* yr = out + (size_t)row * EMB;
    int tid = threadIdx.x;
    float v0 = xr[tid], v1 = xr[tid + 256], v2 = xr[tid + 512];
    float s = v0 + v1 + v2;
    float ss = v0 * v0 + v1 * v1 + v2 * v2;
    #pragma unroll
    for (int i = 1; i < 64; i <<= 1) {
        s  += __shfl_xor(s, i, 64);
        ss += __shfl_xor(ss, i, 64);
    }
    __shared__ float sm[4], sv[4];
    int lane = tid & 63, wid = tid >> 6;
    if (lane == 0) { sm[wid] = s; sv[wid] = ss; }
    __syncthreads();
    float sum = sm[0] + sm[1] + sm[2] + sm[3];
    float sqs = sv[0] + sv[1] + sv[2] + sv[3];
    float mean = sum * (1.0f / EMB);
    float var = sqs * (1.0f / EMB) - mean * mean;
    float rstd = rsqrtf(var + LN_EPS);
    yr[tid]       = __float2bfloat16((v0 - mean) * rstd * g[tid]       + b[tid]);
    yr[tid + 256] = __float2bfloat16((v1 - mean) * rstd * g[tid + 256] + b[tid + 256]);
    yr[tid + 512] = __float2bfloat16((v2 - mean) * rstd * g[tid + 512] + b[tid + 512]);
}

// ---------------- fused per-layer weight transpose ----------------
__global__ void convT4_kernel(const float* __restrict__ aw, const float* __restrict__ pw,
                              const float* __restrict__ fw, const float* __restrict__ mw,
                              __hip_bfloat16* __restrict__ awT, __hip_bfloat16* __restrict__ pwT,
                              __hip_bfloat16* __restrict__ fwT, __hip_bfloat16* __restrict__ mwT) {
    __shared__ float tile[32][33];
    int bid = blockIdx.x;
    const float* W; __hip_bfloat16* Wt; int K, N, t;
    if (bid < 1728)      { W = aw; Wt = awT; K = 768;  N = 2304; t = bid; }
    else if (bid < 2304) { W = pw; Wt = pwT; K = 768;  N = 768;  t = bid - 1728; }
    else if (bid < 4608) { W = fw; Wt = fwT; K = 768;  N = 3072; t = bid - 2304; }
    else                 { W = mw; Wt = mwT; K = 3072; N = 768;  t = bid - 4608; }
    int NT = N >> 5;
    int n0 = (t % NT) << 5, k0 = (t / NT) << 5;
    int tx = threadIdx.x & 31, ty = threadIdx.x >> 5;
    #pragma unroll
    for (int i = ty; i < 32; i += 8)
        tile[i][tx] = W[(size_t)(k0 + i) * N + n0 + tx];
    __syncthreads();
    #pragma unroll
    for (int i = ty; i < 32; i += 8)
        Wt[(size_t)(n0 + i) * K + k0 + tx] = __float2bfloat16(tile[tx][i]);
}

// ---------------- wte convert + pad ----------------
__global__ void conv_wte_kernel(const float* __restrict__ wte, __hip_bfloat16* __restrict__ o) {
    int row = blockIdx.x;
    bool pad = row >= VSZ;
    const float* src = wte + (size_t)row * EMB;
    __hip_bfloat16* dst = o + (size_t)row * EMB;
    for (int e = threadIdx.x; e < EMB; e += blockDim.x)
        dst[e] = __float2bfloat16(pad ? 0.0f : src[e]);
}

// ---------------- bf16 MFMA GEMM: C = act(A @ B^T + bias) [+ res] ----------------
// BK=64, 128x128 tile, 4 waves. Band-blocked XCD order: within each XCD's
// contiguous wg chunk, m' (8-tile band) fastest, n next, band outermost.
// OUT: 0=fp32 Cf, 1=bf16 Cb, 2=qkv-split (cols<1536 -> Cb, else vT transposed)
template <bool GELU, bool RES, int OUT>
__global__ void gemm_bt(const __hip_bfloat16* __restrict__ A, const __hip_bfloat16* __restrict__ B,
                        const float* __restrict__ bias, const float* __restrict__ res,
                        float* __restrict__ Cf, __hip_bfloat16* __restrict__ Cb,
                        __hip_bfloat16* __restrict__ vt,
                        int K, int ldc, int Nclip) {
    __shared__ __hip_bfloat16 Ash[128 * 64];
    __shared__ __hip_bfloat16 Bsh[128 * 64];
    const int tid = threadIdx.x;
    const int lane = tid & 63, wid = tid >> 6;
    const int wr = wid >> 1, wc = wid & 1;

    // XCD swizzle (nwg % 8 == 0 always here) + band-blocked order
    const int nwg = gridDim.x;              // NT * 32
    const int NT = nwg >> 5;
    const int cpx = nwg >> 3;
    const int wg = (blockIdx.x & 7) * cpx + (blockIdx.x >> 3);
    const int bandsz = NT << 3;
    const int band = wg / bandsz;
    const int rem = wg - band * bandsz;
    const int m0 = (band * 8 + (rem & 7)) * 128;
    const int n0 = (rem >> 3) * 128;

    f32x4 acc[4][4] = {};
    const int srow = lane >> 3;          // 0..7 within chunk
    const int scol = (lane & 7) * 8;     // 0..56

    for (int k0 = 0; k0 < K; k0 += 64) {
        #pragma unroll
        for (int it = 0; it < 4; ++it) {
            int c = wid + it * 4;        // chunk 0..15, 8 rows each
            const __hip_bfloat16* ga = A + (size_t)(m0 + c * 8 + srow) * K + k0 + scol;
            load_lds16(ga, &Ash[c * 512]);
            const __hip_bfloat16* gb = B + (size_t)(n0 + c * 8 + srow) * K + k0 + scol;
            load_lds16(gb, &Bsh[c * 512]);
        }
        __syncthreads();
        bf16x8 a[4][2], b[4][2];
        #pragma unroll
        for (int m = 0; m < 4; ++m)
            #pragma unroll
            for (int kk = 0; kk < 2; ++kk)
                a[m][kk] = *(const bf16x8*)&Ash[(wr * 64 + m * 16 + (lane & 15)) * 64 + kk * 32 + (lane >> 4) * 8];
        #pragma unroll
        for (int n = 0; n < 4; ++n)
            #pragma unroll
            for (int kk = 0; kk < 2; ++kk)
                b[n][kk] = *(const bf16x8*)&Bsh[(wc * 64 + n * 16 + (lane & 15)) * 64 + kk * 32 + (lane >> 4) * 8];
        #pragma unroll
        for (int kk = 0; kk < 2; ++kk)
            #pragma unroll
            for (int m = 0; m < 4; ++m)
                #pragma unroll
                for (int n = 0; n < 4; ++n)
                    acc[m][n] = __builtin_amdgcn_mfma_f32_16x16x32_bf16(a[m][kk], b[n][kk], acc[m][n], 0, 0, 0);
        __syncthreads();
    }

    const int crow0 = m0 + wr * 64, ccol0 = n0 + wc * 64;
    #pragma unroll
    for (int m = 0; m < 4; ++m) {
        #pragma unroll
        for (int n = 0; n < 4; ++n) {
            int col = ccol0 + n * 16 + (lane & 15);
            if (col >= Nclip) continue;
            float bv = bias ? bias[col] : 0.0f;
            #pragma unroll
            for (int j = 0; j < 4; ++j) {
                int r = crow0 + m * 16 + (lane >> 4) * 4 + j;
                float v = acc[m][n][j] + bv;
                if (GELU) {
                    float t = 0.7978845608028654f * (v + 0.044715f * v * v * v);
                    v = 0.5f * v * (1.0f + tanhf(t));
                }
                if (RES) v += res[(size_t)r * ldc + col];
                if (OUT == 0) Cf[(size_t)r * ldc + col] = v;
                else if (OUT == 1) Cb[(size_t)r * ldc + col] = __float2bfloat16(v);
                else {
                    if (col < 2 * EMB) Cb[(size_t)r * (2 * EMB) + col] = __float2bfloat16(v);
                    else {
                        int hh = (col - 2 * EMB) >> 6, dd = (col - 2 * EMB) & 63;
                        int bb = r >> 10, tt = r & 1023;
                        vt[(((size_t)bb * NH + hh) * 64 + dd) * TSEQ + tt] = __float2bfloat16(v);
                    }
                }
            }
        }
    }
}

// ---------------- MFMA flash attention ----------------
__global__ __launch_bounds__(256) void flash_attn(const __hip_bfloat16* __restrict__ qk,
                                                  const __hip_bfloat16* __restrict__ vT,
                                                  __hip_bfloat16* __restrict__ y) {
    const int qt = blockIdx.x, h = blockIdx.y, b = blockIdx.z;
    const int tid = threadIdx.x;
    const int lane = tid & 63, w = tid >> 6;
    const int g = lane >> 4, lr = lane & 15;

    __shared__ char KshB[64 * 128];
    __shared__ char VshB[64 * 128];
    __shared__ char PshB[4][16 * 128];

    const __hip_bfloat16* qrow = qk + ((size_t)(b * TSEQ + qt * 64 + w * 16 + lr)) * 1536 + h * 64;
    bf16x8 qf0 = *(const bf16x8*)(qrow + g * 8);
    bf16x8 qf1 = *(const bf16x8*)(qrow + 32 + g * 8);

    float m[4], l[4];
    f32x4 o[4];
    #pragma unroll
    for (int j = 0; j < 4; ++j) { m[j] = -1e30f; l[j] = 0.0f; }
    #pragma unroll
    for (int n = 0; n < 4; ++n) o[n] = (f32x4){0.f, 0.f, 0.f, 0.f};

    const int r0 = tid >> 3;
    const int c0 = (tid & 7) * 8;

    for (int kt = 0; kt <= qt; ++kt) {
        __syncthreads();
        #pragma unroll
        for (int it = 0; it < 2; ++it) {
            int r = r0 + it * 32;
            bf16x8 kv = *(const bf16x8*)(qk + ((size_t)(b * TSEQ + kt * 64 + r)) * 1536 + EMB + h * 64 + c0);
            *(bf16x8*)(KshB + ((r * 128 + c0 * 2) ^ ((r & 7) << 4))) = kv;
            bf16x8 vv = *(const bf16x8*)(vT + (((size_t)(b * NH + h)) * 64 + r) * TSEQ + kt * 64 + c0);
            *(bf16x8*)(VshB + ((r * 128 + c0 * 2) ^ ((r & 7) << 4))) = vv;
        }
        __syncthreads();

        f32x4 s[4] = {};
        #pragma unroll
        for (int n = 0; n < 4; ++n) {
            int kr = n * 16 + lr;
            bf16x8 kb0 = *(const bf16x8*)(KshB + ((kr * 128 + g * 16) ^ ((kr & 7) << 4)));
            bf16x8 kb1 = *(const bf16x8*)(KshB + ((kr * 128 + 64 + g * 16) ^ ((kr & 7) << 4)));
            s[n] = __builtin_amdgcn_mfma_f32_16x16x32_bf16(qf0, kb0, s[n], 0, 0, 0);
            s[n] = __builtin_amdgcn_mfma_f32_16x16x32_bf16(qf1, kb1, s[n], 0, 0, 0);
        }

        const bool diag = (kt == qt);
        float tmax[4] = {-1e30f, -1e30f, -1e30f, -1e30f};
        #pragma unroll
        for (int n = 0; n < 4; ++n)
            #pragma unroll
            for (int j = 0; j < 4; ++j) {
                float v = s[n][j] * 0.125f;
                if (diag && (n * 16 + lr > w * 16 + g * 4 + j)) v = -1e30f;
                s[n][j] = v;
                tmax[j] = fmaxf(tmax[j], v);
            }
        #pragma unroll
        for (int j = 0; j < 4; ++j)
            #pragma unroll
            for (int i = 1; i < 16; i <<= 1)
                tmax[j] = fmaxf(tmax[j], __shfl_xor(tmax[j], i, 64));

        float lsum[4] = {0.f, 0.f, 0.f, 0.f};
        float pexp[4][4];
        #pragma unroll
        for (int j = 0; j < 4; ++j) {
            float mn = fmaxf(m[j], tmax[j]);
            float sc = __expf(m[j] - mn);
            l[j] *= sc;
            m[j] = mn;
            #pragma unroll
            for (int n = 0; n < 4; ++n) {
                float p = __expf(s[n][j] - mn);
                pexp[n][j] = p;
                lsum[j] += p;
                o[n][j] *= sc;
            }
        }
        #pragma unroll
        for (int j = 0; j < 4; ++j) {
            #pragma unroll
            for (int i = 1; i < 16; i <<= 1) lsum[j] += __shfl_xor(lsum[j], i, 64);
            l[j] += lsum[j];
        }

        char* P = PshB[w];
        #pragma unroll
        for (int n = 0; n < 4; ++n)
            #pragma unroll
            for (int j = 0; j < 4; ++j) {
                int rw = g * 4 + j;
                *(__hip_bfloat16*)(P + ((rw * 128 + (n * 16 + lr) * 2) ^ ((rw & 7) << 4))) =
                    __float2bfloat16(pexp[n][j]);
            }
        asm volatile("s_waitcnt lgkmcnt(0)" ::: "memory");
        bf16x8 pa0 = *(const bf16x8*)(P + ((lr * 128 + g * 16) ^ ((lr & 7) << 4)));
        bf16x8 pa1 = *(const bf16x8*)(P + ((lr * 128 + 64 + g * 16) ^ ((lr & 7) << 4)));
        #pragma unroll
        for (int n = 0; n < 4; ++n) {
            int vr = n * 16 + lr;
            bf16x8 vb0 = *(const bf16x8*)(VshB + ((vr * 128 + g * 16) ^ ((vr & 7) << 4)));
            bf16x8 vb1 = *(const bf16x8*)(VshB + ((vr * 128 + 64 + g * 16) ^ ((vr & 7) << 4)));
            o[n] = __builtin_amdgcn_mfma_f32_16x16x32_bf16(pa0, vb0, o[n], 0, 0, 0);
            o[n] = __builtin_amdgcn_mfma_f32_16x16x32_bf16(pa1, vb1, o[n], 0, 0, 0);
        }
    }

    #pragma unroll
    for (int j = 0; j < 4; ++j) {
        float inv = 1.0f / l[j];
        int row = b * TSEQ + qt * 64 + w * 16 + g * 4 + j;
        #pragma unroll
        for (int n = 0; n < 4; ++n)
            y[(size_t)row * EMB + h * 64 + n * 16 + lr] = __float2bfloat16(o[n][j] * inv);
    }
}

// ---------------- launcher ----------------
extern "C" void kernel_launch(void* const* d_in, const int* in_sizes, int n_in,
                              void* d_out, int out_size, void* d_ws, size_t ws_size,
                              hipStream_t stream) {
    const int*   idx     = (const int*)d_in[0];
    const float* wte     = (const float*)d_in[1];
    const float* wpe     = (const float*)d_in[2];
    const float* ln1_g   = (const float*)d_in[3];
    const float* ln1_b   = (const float*)d_in[4];
    const float* attn_w  = (const float*)d_in[5];
    const float* attn_b  = (const float*)d_in[6];
    const float* proj_w  = (const float*)d_in[7];
    const float* proj_b  = (const float*)d_in[8];
    const float* ln2_g   = (const float*)d_in[9];
    const float* ln2_b   = (const float*)d_in[10];
    const float* fc_w    = (const float*)d_in[11];
    const float* fc_b    = (const float*)d_in[12];
    const float* mproj_w = (const float*)d_in[13];
    const float* mproj_b = (const float*)d_in[14];
    const float* lnf_g   = (const float*)d_in[15];
    const float* lnf_b   = (const float*)d_in[16];
    float* out = (float*)d_out;

    char* w = (char*)d_ws;
    float* x = (float*)w;                      w += (size_t)MROWS * EMB * 4;
    __hip_bfloat16* qkb = (__hip_bfloat16*)w;  w += (size_t)MROWS * 2 * EMB * 2;
    __hip_bfloat16* vTb = (__hip_bfloat16*)w;  w += (size_t)NB * NH * 64 * TSEQ * 2;
    __hip_bfloat16* h = (__hip_bfloat16*)w;    w += (size_t)MROWS * EMB * 2;
    __hip_bfloat16* y = (__hip_bfloat16*)w;    w += (size_t)MROWS * EMB * 2;
    __hip_bfloat16* g = (__hip_bfloat16*)w;    w += (size_t)MROWS * 4 * EMB * 2;
    __hip_bfloat16* wqkvT = (__hip_bfloat16*)w;   w += (size_t)3 * EMB * EMB * 2;
    __hip_bfloat16* wprojT = (__hip_bfloat16*)w;  w += (size_t)EMB * EMB * 2;
    __hip_bfloat16* wfcT = (__hip_bfloat16*)w;    w += (size_t)4 * EMB * EMB * 2;
    __hip_bfloat16* wmprojT = (__hip_bfloat16*)w; w += (size_t)4 * EMB * EMB * 2;
    __hip_bfloat16* wteB = (__hip_bfloat16*)w;    w += (size_t)VPAD * EMB * 2;

    dim3 blk256(256);

    embed_kernel<<<MROWS, blk256, 0, stream>>>(idx, wte, wpe, x);
    conv_wte_kernel<<<VPAD, blk256, 0, stream>>>(wte, wteB);

    for (int l = 0; l < NLAYER; l++) {
        const float* aw = attn_w + (size_t)l * EMB * 3 * EMB;
        const float* ab = attn_b + (size_t)l * 3 * EMB;
        const float* pw = proj_w + (size_t)l * EMB * EMB;
        const float* pb = proj_b + (size_t)l * EMB;
        const float* fw = fc_w   + (size_t)l * EMB * 4 * EMB;
        const float* fb = fc_b   + (size_t)l * 4 * EMB;
        const float* mw = mproj_w + (size_t)l * 4 * EMB * EMB;
        const float* mb = mproj_b + (size_t)l * EMB;

        ln_kernel<<<MROWS, blk256, 0, stream>>>(x, ln1_g + l * EMB, ln1_b + l * EMB, h);
        convT4_kernel<<<6912, blk256, 0, stream>>>(aw, pw, fw, mw, wqkvT, wprojT, wfcT, wmprojT);

        gemm_bt<false, false, 2><<<dim3((3 * EMB / 128) * 32), blk256, 0, stream>>>(
            h, wqkvT, ab, nullptr, nullptr, qkb, vTb, EMB, 3 * EMB, 3 * EMB);

        flash_attn<<<dim3(TSEQ / 64, NH, NB), blk256, 0, stream>>>(qkb, vTb, y);

        gemm_bt<false, true, 0><<<dim3((EMB / 128) * 32), blk256, 0, stream>>>(
            y, wprojT, pb, x, x, nullptr, nullptr, EMB, EMB, EMB);

        ln_kernel<<<MROWS, blk256, 0, stream>>>(x, ln2_g + l * EMB, ln2_b + l * EMB, h);

        gemm_bt<true, false, 1><<<dim3((4 * EMB / 128) * 32), blk256, 0, stream>>>(
            h, wfcT, fb, nullptr, nullptr, g, nullptr, EMB, 4 * EMB, 4 * EMB);

        gemm_bt<false, true, 0><<<dim3((EMB / 128) * 32), blk256, 0, stream>>>(
            g, wmprojT, mb, x, x, nullptr, nullptr, 4 * EMB, EMB, EMB);
    }

    ln_kernel<<<MROWS, blk256, 0, stream>>>(x, lnf_g, lnf_b, h);

    gemm_bt<false, false, 0><<<dim3((VPAD / 128) * 32), blk256, 0, stream>>>(
        h, wteB, nullptr, nullptr, out, nullptr, nullptr, EMB, VSZ, VSZ);
}

// Round 6
// 3193.286 us; speedup vs baseline: 12.1713x; 1.0992x over previous
//
#include <hip/hip_runtime.h>
#include <hip/hip_bf16.h>
#include <math.h>

#define VSZ 50257
#define VPAD 50304
#define NLAYER 12
#define NH 12
#define EMB 768
#define TSEQ 1024
#define NB 4
#define MROWS (NB * TSEQ)   // 4096
#define DHEAD 64
#define LN_EPS 1e-5f

typedef __attribute__((ext_vector_type(8))) short bf16x8;
typedef __attribute__((ext_vector_type(4))) float f32x4;

__device__ __forceinline__ void load_lds16(const void* g, void* l) {
    __builtin_amdgcn_global_load_lds((const __attribute__((address_space(1))) unsigned int*)g,
                                     (__attribute__((address_space(3))) unsigned int*)l,
                                     16, 0, 0);
}

// ---------------- embedding ----------------
__global__ void embed_kernel(const int* __restrict__ idx, const float* __restrict__ wte,
                             const float* __restrict__ wpe, float* __restrict__ x) {
    int row = blockIdx.x;
    int t = row & (TSEQ - 1);
    int tok = idx[row];
    const float* wt = wte + (size_t)tok * EMB;
    const float* wp = wpe + (size_t)t * EMB;
    float* xo = x + (size_t)row * EMB;
    for (int e = threadIdx.x; e < EMB; e += blockDim.x)
        xo[e] = wt[e] + wp[e];
}

// ---------------- layernorm: fp32 in -> bf16 out ----------------
__global__ void ln_kernel(const float* __restrict__ x, const float* __restrict__ g,
                          const float* __restrict__ b, __hip_bfloat16* __restrict__ out) {
    int row = blockIdx.x;
    const float* xr = x + (size_t)row * EMB;
    __hip_bfloat16* yr = out + (size_t)row * EMB;
    int tid = threadIdx.x;
    float v0 = xr[tid], v1 = xr[tid + 256], v2 = xr[tid + 512];
    float s = v0 + v1 + v2;
    float ss = v0 * v0 + v1 * v1 + v2 * v2;
    #pragma unroll
    for (int i = 1; i < 64; i <<= 1) {
        s  += __shfl_xor(s, i, 64);
        ss += __shfl_xor(ss, i, 64);
    }
    __shared__ float sm[4], sv[4];
    int lane = tid & 63, wid = tid >> 6;
    if (lane == 0) { sm[wid] = s; sv[wid] = ss; }
    __syncthreads();
    float sum = sm[0] + sm[1] + sm[2] + sm[3];
    float sqs = sv[0] + sv[1] + sv[2] + sv[3];
    float mean = sum * (1.0f / EMB);
    float var = sqs * (1.0f / EMB) - mean * mean;
    float rstd = rsqrtf(var + LN_EPS);
    yr[tid]       = __float2bfloat16((v0 - mean) * rstd * g[tid]       + b[tid]);
    yr[tid + 256] = __float2bfloat16((v1 - mean) * rstd * g[tid + 256] + b[tid + 256]);
    yr[tid + 512] = __float2bfloat16((v2 - mean) * rstd * g[tid + 512] + b[tid + 512]);
}

// ---------------- fused per-layer weight transpose ----------------
__global__ void convT4_kernel(const float* __restrict__ aw, const float* __restrict__ pw,
                              const float* __restrict__ fw, const float* __restrict__ mw,
                              __hip_bfloat16* __restrict__ awT, __hip_bfloat16* __restrict__ pwT,
                              __hip_bfloat16* __restrict__ fwT, __hip_bfloat16* __restrict__ mwT) {
    __shared__ float tile[32][33];
    int bid = blockIdx.x;
    const float* W; __hip_bfloat16* Wt; int K, N, t;
    if (bid < 1728)      { W = aw; Wt = awT; K = 768;  N = 2304; t = bid; }
    else if (bid < 2304) { W = pw; Wt = pwT; K = 768;  N = 768;  t = bid - 1728; }
    else if (bid < 4608) { W = fw; Wt = fwT; K = 768;  N = 3072; t = bid - 2304; }
    else                 { W = mw; Wt = mwT; K = 3072; N = 768;  t = bid - 4608; }
    int NT = N >> 5;
    int n0 = (t % NT) << 5, k0 = (t / NT) << 5;
    int tx = threadIdx.x & 31, ty = threadIdx.x >> 5;
    #pragma unroll
    for (int i = ty; i < 32; i += 8)
        tile[i][tx] = W[(size_t)(k0 + i) * N + n0 + tx];
    __syncthreads();
    #pragma unroll
    for (int i = ty; i < 32; i += 8)
        Wt[(size_t)(n0 + i) * K + k0 + tx] = __float2bfloat16(tile[tx][i]);
}

// ---------------- wte convert + pad ----------------
__global__ void conv_wte_kernel(const float* __restrict__ wte, __hip_bfloat16* __restrict__ o) {
    int row = blockIdx.x;
    bool pad = row >= VSZ;
    const float* src = wte + (size_t)row * EMB;
    __hip_bfloat16* dst = o + (size_t)row * EMB;
    for (int e = threadIdx.x; e < EMB; e += blockDim.x)
        dst[e] = __float2bfloat16(pad ? 0.0f : src[e]);
}

// ---------------- bf16 MFMA GEMM: C = act(A @ B^T + bias) [+ res] ----------------
// BK=64, 128x128 tile, 4 waves, band-blocked XCD order (8-m-tile bands, L2-resident).
// LDS layout is XOR-swizzled per rule #21: global_load_lds writes LINEARLY, the
// 16B source granule is pre-swizzled per lane (gl = gp ^ (row&7)), and ds_read
// applies the same XOR -> conflict-free b128 fragment reads at 128B row stride.
// OUT: 0=fp32 Cf, 1=bf16 Cb, 2=qkv-split (cols<1536 -> Cb, else vT transposed)
template <bool GELU, bool RES, int OUT>
__global__ void gemm_bt(const __hip_bfloat16* __restrict__ A, const __hip_bfloat16* __restrict__ B,
                        const float* __restrict__ bias, const float* __restrict__ res,
                        float* __restrict__ Cf, __hip_bfloat16* __restrict__ Cb,
                        __hip_bfloat16* __restrict__ vt,
                        int K, int ldc, int Nclip) {
    __shared__ __hip_bfloat16 Ash[128 * 64];
    __shared__ __hip_bfloat16 Bsh[128 * 64];
    const int tid = threadIdx.x;
    const int lane = tid & 63, wid = tid >> 6;
    const int wr = wid >> 1, wc = wid & 1;

    // XCD swizzle (nwg % 8 == 0 always here) + band-blocked order
    const int nwg = gridDim.x;              // NT * 32
    const int NT = nwg >> 5;
    const int cpx = nwg >> 3;
    const int wg = (blockIdx.x & 7) * cpx + (blockIdx.x >> 3);
    const int bandsz = NT << 3;
    const int band = wg / bandsz;
    const int rem = wg - band * bandsz;
    const int m0 = (band * 8 + (rem & 7)) * 128;
    const int n0 = (rem >> 3) * 128;

    f32x4 acc[4][4] = {};
    const int srow = lane >> 3;                  // 0..7 (row within 8-row chunk)
    const int scol = ((lane & 7) ^ srow) * 8;    // SWIZZLED source granule

    const int lr16 = lane & 15;
    const int hi = lane >> 4;

    for (int k0 = 0; k0 < K; k0 += 64) {
        #pragma unroll
        for (int it = 0; it < 4; ++it) {
            int c = wid + it * 4;        // chunk 0..15, 8 rows each
            const __hip_bfloat16* ga = A + (size_t)(m0 + c * 8 + srow) * K + k0 + scol;
            load_lds16(ga, &Ash[c * 512]);
            const __hip_bfloat16* gb = B + (size_t)(n0 + c * 8 + srow) * K + k0 + scol;
            load_lds16(gb, &Bsh[c * 512]);
        }
        __syncthreads();
        bf16x8 a[4][2], b[4][2];
        #pragma unroll
        for (int m = 0; m < 4; ++m)
            #pragma unroll
            for (int kk = 0; kk < 2; ++kk) {
                int ra = wr * 64 + m * 16 + lr16;
                int ca = (kk * 32 + hi * 8) ^ ((ra & 7) * 8);
                a[m][kk] = *(const bf16x8*)&Ash[ra * 64 + ca];
            }
        #pragma unroll
        for (int n = 0; n < 4; ++n)
            #pragma unroll
            for (int kk = 0; kk < 2; ++kk) {
                int rb = wc * 64 + n * 16 + lr16;
                int cb = (kk * 32 + hi * 8) ^ ((rb & 7) * 8);
                b[n][kk] = *(const bf16x8*)&Bsh[rb * 64 + cb];
            }
        #pragma unroll
        for (int kk = 0; kk < 2; ++kk)
            #pragma unroll
            for (int m = 0; m < 4; ++m)
                #pragma unroll
                for (int n = 0; n < 4; ++n)
                    acc[m][n] = __builtin_amdgcn_mfma_f32_16x16x32_bf16(a[m][kk], b[n][kk], acc[m][n], 0, 0, 0);
        __syncthreads();
    }

    const int crow0 = m0 + wr * 64, ccol0 = n0 + wc * 64;
    #pragma unroll
    for (int m = 0; m < 4; ++m) {
        #pragma unroll
        for (int n = 0; n < 4; ++n) {
            int col = ccol0 + n * 16 + (lane & 15);
            if (col >= Nclip) continue;
            float bv = bias ? bias[col] : 0.0f;
            #pragma unroll
            for (int j = 0; j < 4; ++j) {
                int r = crow0 + m * 16 + (lane >> 4) * 4 + j;
                float v = acc[m][n][j] + bv;
                if (GELU) {
                    float t = 0.7978845608028654f * (v + 0.044715f * v * v * v);
                    v = 0.5f * v * (1.0f + tanhf(t));
                }
                if (RES) v += res[(size_t)r * ldc + col];
                if (OUT == 0) Cf[(size_t)r * ldc + col] = v;
                else if (OUT == 1) Cb[(size_t)r * ldc + col] = __float2bfloat16(v);
                else {
                    if (col < 2 * EMB) Cb[(size_t)r * (2 * EMB) + col] = __float2bfloat16(v);
                    else {
                        int hh = (col - 2 * EMB) >> 6, dd = (col - 2 * EMB) & 63;
                        int bb = r >> 10, tt = r & 1023;
                        vt[(((size_t)bb * NH + hh) * 64 + dd) * TSEQ + tt] = __float2bfloat16(v);
                    }
                }
            }
        }
    }
}

// ---------------- MFMA flash attention ----------------
__global__ __launch_bounds__(256) void flash_attn(const __hip_bfloat16* __restrict__ qk,
                                                  const __hip_bfloat16* __restrict__ vT,
                                                  __hip_bfloat16* __restrict__ y) {
    const int qt = blockIdx.x, h = blockIdx.y, b = blockIdx.z;
    const int tid = threadIdx.x;
    const int lane = tid & 63, w = tid >> 6;
    const int g = lane >> 4, lr = lane & 15;

    __shared__ char KshB[64 * 128];
    __shared__ char VshB[64 * 128];
    __shared__ char PshB[4][16 * 128];

    const __hip_bfloat16* qrow = qk + ((size_t)(b * TSEQ + qt * 64 + w * 16 + lr)) * 1536 + h * 64;
    bf16x8 qf0 = *(const bf16x8*)(qrow + g * 8);
    bf16x8 qf1 = *(const bf16x8*)(qrow + 32 + g * 8);

    float m[4], l[4];
    f32x4 o[4];
    #pragma unroll
    for (int j = 0; j < 4; ++j) { m[j] = -1e30f; l[j] = 0.0f; }
    #pragma unroll
    for (int n = 0; n < 4; ++n) o[n] = (f32x4){0.f, 0.f, 0.f, 0.f};

    const int r0 = tid >> 3;
    const int c0 = (tid & 7) * 8;

    for (int kt = 0; kt <= qt; ++kt) {
        __syncthreads();
        #pragma unroll
        for (int it = 0; it < 2; ++it) {
            int r = r0 + it * 32;
            bf16x8 kv = *(const bf16x8*)(qk + ((size_t)(b * TSEQ + kt * 64 + r)) * 1536 + EMB + h * 64 + c0);
            *(bf16x8*)(KshB + ((r * 128 + c0 * 2) ^ ((r & 7) << 4))) = kv;
            bf16x8 vv = *(const bf16x8*)(vT + (((size_t)(b * NH + h)) * 64 + r) * TSEQ + kt * 64 + c0);
            *(bf16x8*)(VshB + ((r * 128 + c0 * 2) ^ ((r & 7) << 4))) = vv;
        }
        __syncthreads();

        f32x4 s[4] = {};
        #pragma unroll
        for (int n = 0; n < 4; ++n) {
            int kr = n * 16 + lr;
            bf16x8 kb0 = *(const bf16x8*)(KshB + ((kr * 128 + g * 16) ^ ((kr & 7) << 4)));
            bf16x8 kb1 = *(const bf16x8*)(KshB + ((kr * 128 + 64 + g * 16) ^ ((kr & 7) << 4)));
            s[n] = __builtin_amdgcn_mfma_f32_16x16x32_bf16(qf0, kb0, s[n], 0, 0, 0);
            s[n] = __builtin_amdgcn_mfma_f32_16x16x32_bf16(qf1, kb1, s[n], 0, 0, 0);
        }

        const bool diag = (kt == qt);
        float tmax[4] = {-1e30f, -1e30f, -1e30f, -1e30f};
        #pragma unroll
        for (int n = 0; n < 4; ++n)
            #pragma unroll
            for (int j = 0; j < 4; ++j) {
                float v = s[n][j] * 0.125f;
                if (diag && (n * 16 + lr > w * 16 + g * 4 + j)) v = -1e30f;
                s[n][j] = v;
                tmax[j] = fmaxf(tmax[j], v);
            }
        #pragma unroll
        for (int j = 0; j < 4; ++j)
            #pragma unroll
            for (int i = 1; i < 16; i <<= 1)
                tmax[j] = fmaxf(tmax[j], __shfl_xor(tmax[j], i, 64));

        float lsum[4] = {0.f, 0.f, 0.f, 0.f};
        float pexp[4][4];
        #pragma unroll
        for (int j = 0; j < 4; ++j) {
            float mn = fmaxf(m[j], tmax[j]);
            float sc = __expf(m[j] - mn);
            l[j] *= sc;
            m[j] = mn;
            #pragma unroll
            for (int n = 0; n < 4; ++n) {
                float p = __expf(s[n][j] - mn);
                pexp[n][j] = p;
                lsum[j] += p;
                o[n][j] *= sc;
            }
        }
        #pragma unroll
        for (int j = 0; j < 4; ++j) {
            #pragma unroll
            for (int i = 1; i < 16; i <<= 1) lsum[j] += __shfl_xor(lsum[j], i, 64);
            l[j] += lsum[j];
        }

        char* P = PshB[w];
        #pragma unroll
        for (int n = 0; n < 4; ++n)
            #pragma unroll
            for (int j = 0; j < 4; ++j) {
                int rw = g * 4 + j;
                *(__hip_bfloat16*)(P + ((rw * 128 + (n * 16 + lr) * 2) ^ ((rw & 7) << 4))) =
                    __float2bfloat16(pexp[n][j]);
            }
        asm volatile("s_waitcnt lgkmcnt(0)" ::: "memory");
        bf16x8 pa0 = *(const bf16x8*)(P + ((lr * 128 + g * 16) ^ ((lr & 7) << 4)));
        bf16x8 pa1 = *(const bf16x8*)(P + ((lr * 128 + 64 + g * 16) ^ ((lr & 7) << 4)));
        #pragma unroll
        for (int n = 0; n < 4; ++n) {
            int vr = n * 16 + lr;
            bf16x8 vb0 = *(const bf16x8*)(VshB + ((vr * 128 + g * 16) ^ ((vr & 7) << 4)));
            bf16x8 vb1 = *(const bf16x8*)(VshB + ((vr * 128 + 64 + g * 16) ^ ((vr & 7) << 4)));
            o[n] = __builtin_amdgcn_mfma_f32_16x16x32_bf16(pa0, vb0, o[n], 0, 0, 0);
            o[n] = __builtin_amdgcn_mfma_f32_16x16x32_bf16(pa1, vb1, o[n], 0, 0, 0);
        }
    }

    #pragma unroll
    for (int j = 0; j < 4; ++j) {
        float inv = 1.0f / l[j];
        int row = b * TSEQ + qt * 64 + w * 16 + g * 4 + j;
        #pragma unroll
        for (int n = 0; n < 4; ++n)
            y[(size_t)row * EMB + h * 64 + n * 16 + lr] = __float2bfloat16(o[n][j] * inv);
    }
}

// ---------------- launcher ----------------
extern "C" void kernel_launch(void* const* d_in, const int* in_sizes, int n_in,
                              void* d_out, int out_size, void* d_ws, size_t ws_size,
                              hipStream_t stream) {
    const int*   idx     = (const int*)d_in[0];
    const float* wte     = (const float*)d_in[1];
    const float* wpe     = (const float*)d_in[2];
    const float* ln1_g   = (const float*)d_in[3];
    const float* ln1_b   = (const float*)d_in[4];
    const float* attn_w  = (const float*)d_in[5];
    const float* attn_b  = (const float*)d_in[6];
    const float* proj_w  = (const float*)d_in[7];
    const float* proj_b  = (const float*)d_in[8];
    const float* ln2_g   = (const float*)d_in[9];
    const float* ln2_b   = (const float*)d_in[10];
    const float* fc_w    = (const float*)d_in[11];
    const float* fc_b    = (const float*)d_in[12];
    const float* mproj_w = (const float*)d_in[13];
    const float* mproj_b = (const float*)d_in[14];
    const float* lnf_g   = (const float*)d_in[15];
    const float* lnf_b   = (const float*)d_in[16];
    float* out = (float*)d_out;

    char* w = (char*)d_ws;
    float* x = (float*)w;                      w += (size_t)MROWS * EMB * 4;
    __hip_bfloat16* qkb = (__hip_bfloat16*)w;  w += (size_t)MROWS * 2 * EMB * 2;
    __hip_bfloat16* vTb = (__hip_bfloat16*)w;  w += (size_t)NB * NH * 64 * TSEQ * 2;
    __hip_bfloat16* h = (__hip_bfloat16*)w;    w += (size_t)MROWS * EMB * 2;
    __hip_bfloat16* y = (__hip_bfloat16*)w;    w += (size_t)MROWS * EMB * 2;
    __hip_bfloat16* g = (__hip_bfloat16*)w;    w += (size_t)MROWS * 4 * EMB * 2;
    __hip_bfloat16* wqkvT = (__hip_bfloat16*)w;   w += (size_t)3 * EMB * EMB * 2;
    __hip_bfloat16* wprojT = (__hip_bfloat16*)w;  w += (size_t)EMB * EMB * 2;
    __hip_bfloat16* wfcT = (__hip_bfloat16*)w;    w += (size_t)4 * EMB * EMB * 2;
    __hip_bfloat16* wmprojT = (__hip_bfloat16*)w; w += (size_t)4 * EMB * EMB * 2;
    __hip_bfloat16* wteB = (__hip_bfloat16*)w;    w += (size_t)VPAD * EMB * 2;

    dim3 blk256(256);

    embed_kernel<<<MROWS, blk256, 0, stream>>>(idx, wte, wpe, x);
    conv_wte_kernel<<<VPAD, blk256, 0, stream>>>(wte, wteB);

    for (int l = 0; l < NLAYER; l++) {
        const float* aw = attn_w + (size_t)l * EMB * 3 * EMB;
        const float* ab = attn_b + (size_t)l * 3 * EMB;
        const float* pw = proj_w + (size_t)l * EMB * EMB;
        const float* pb = proj_b + (size_t)l * EMB;
        const float* fw = fc_w   + (size_t)l * EMB * 4 * EMB;
        const float* fb = fc_b   + (size_t)l * 4 * EMB;
        const float* mw = mproj_w + (size_t)l * 4 * EMB * EMB;
        const float* mb = mproj_b + (size_t)l * EMB;

        ln_kernel<<<MROWS, blk256, 0, stream>>>(x, ln1_g + l * EMB, ln1_b + l * EMB, h);
        convT4_kernel<<<6912, blk256, 0, stream>>>(aw, pw, fw, mw, wqkvT, wprojT, wfcT, wmprojT);

        gemm_bt<false, false, 2><<<dim3((3 * EMB / 128) * 32), blk256, 0, stream>>>(
            h, wqkvT, ab, nullptr, nullptr, qkb, vTb, EMB, 3 * EMB, 3 * EMB);

        flash_attn<<<dim3(TSEQ / 64, NH, NB), blk256, 0, stream>>>(qkb, vTb, y);

        gemm_bt<false, true, 0><<<dim3((EMB / 128) * 32), blk256, 0, stream>>>(
            y, wprojT, pb, x, x, nullptr, nullptr, EMB, EMB, EMB);

        ln_kernel<<<MROWS, blk256, 0, stream>>>(x, ln2_g + l * EMB, ln2_b + l * EMB, h);

        gemm_bt<true, false, 1><<<dim3((4 * EMB / 128) * 32), blk256, 0, stream>>>(
            h, wfcT, fb, nullptr, nullptr, g, nullptr, EMB, 4 * EMB, 4 * EMB);

        gemm_bt<false, true, 0><<<dim3((EMB / 128) * 32), blk256, 0, stream>>>(
            g, wmprojT, mb, x, x, nullptr, nullptr, 4 * EMB, EMB, EMB);
    }

    ln_kernel<<<MROWS, blk256, 0, stream>>>(x, lnf_g, lnf_b, h);

    gemm_bt<false, false, 0><<<dim3((VPAD / 128) * 32), blk256, 0, stream>>>(
        h, wteB, nullptr, nullptr, out, nullptr, nullptr, EMB, VSZ, VSZ);
}